// Round 1
// 769.052 us; speedup vs baseline: 3.6079x; 3.6079x over previous
//
#include <hip/hip_runtime.h>

// CrossAttention: x_qkv->K,V ; y_q->Q ; CLS full attn + patch 3x3 local attn ; @Wo+bo
// I/O fp32, internals bf16 MFMA GEMMs (weights pre-transposed to bf16; A-tiles
// converted during LDS staging), fp32 attention math.
//
// THIS VERSION: full-batch processing (no 16-way chunking). Workspace poison
// fill = 302592 KiB = exactly 4 activation buffers -> ws_size ~295 MiB, so
// full fp32 K,V,Q (3 x 77.5 MB) + bf16 weights (4.7 MB) fit. 5 launches total:
//   transpose(x4 fused) -> fused QKV GEMM (18x197 blocks) -> cls_attn ->
//   patch_attn -> O GEMM (6x197 blocks).
// Fallback to the old 16-chunk flow if ws_size is smaller than needed.

typedef __bf16 bf16x8 __attribute__((ext_vector_type(8)));
typedef float f32x4 __attribute__((ext_vector_type(4)));

#define NTOK 197
#define BATCH 128
#define MROWS (BATCH * NTOK)            // 25216 = 197 * 128, exact M tiles
#define MTILES_FULL (MROWS / 128)       // 197
#define W_ELEMS ((size_t)768 * 768)
#define BUF_ELEMS_FULL ((size_t)MROWS * 768)

// fallback chunked config (old behavior)
#define CHUNK_B 8
#define NCHUNK 16
#define MC_CHUNK (CHUNK_B * NTOK)       // 1576
#define MTILES_CHUNK 13                 // ceil(1576/128)
#define BUF_ELEMS_CHUNK ((size_t)MC_CHUNK * 768)

__device__ __forceinline__ unsigned short f2b(float f) {
  unsigned int x = __float_as_uint(f);
  x += 0x7fff + ((x >> 16) & 1);          // RNE
  return (unsigned short)(x >> 16);
}

// -------- weight transpose+convert: Wt[n*768+k] = bf16(W[k*768+n]) --------
// blockIdx.y selects which of the 4 weights.
__global__ void transpose768x4(const float* __restrict__ s0, const float* __restrict__ s1,
                               const float* __restrict__ s2, const float* __restrict__ s3,
                               unsigned short* __restrict__ d0, unsigned short* __restrict__ d1,
                               unsigned short* __restrict__ d2, unsigned short* __restrict__ d3) {
  const float* src;
  unsigned short* dst;
  switch (blockIdx.y) {
    case 0: src = s0; dst = d0; break;
    case 1: src = s1; dst = d1; break;
    case 2: src = s2; dst = d2; break;
    default: src = s3; dst = d3; break;
  }
  int idx = blockIdx.x * 256 + threadIdx.x;   // 589824 total
  int n = idx / 768, k = idx % 768;
  dst[idx] = f2b(src[k * 768 + n]);
}

// -------- bf16 MFMA GEMM body: C[M,768] = A[M,768] @ Wt^T + bias (fp32 io) --
// A fp32 (converted to bf16 in staging), Wt bf16 N-major, C fp32.
// 128x128 block tile, BK=32, 4 waves (2x2), wave = 4x4 MFMA 16x16x32 tiles.
__device__ __forceinline__ void gemm_body(
    const float* __restrict__ A, const unsigned short* __restrict__ Wt,
    const float* __restrict__ bias, float* __restrict__ C,
    const int row0, const int n0, const int Mrows, unsigned short* sAB) {
  const int tid = threadIdx.x;
  const int l = tid & 63, w = tid >> 6;
  const int wr = w >> 1, wc = w & 1;
  const int lane16 = l & 15, quad = l >> 4;

  f32x4 acc[4][4] = {};

  for (int kt = 0; kt < 24; ++kt) {
    const int k0 = kt * 32;
    // stage: 512 chunks of 8 elems for A (fp32->bf16) and B (bf16 copy)
    #pragma unroll
    for (int i = 0; i < 2; ++i) {
      const int ch = i * 256 + tid;          // 0..511
      const int rr = ch >> 2;                // tile row
      const int c8 = (ch & 3) * 8;           // elem offset within 32-wide k
      int ra = row0 + rr; if (ra > Mrows - 1) ra = Mrows - 1;   // M edge clamp
      const float* ap = A + (size_t)ra * 768 + k0 + c8;
      float4 f0 = *(const float4*)ap;
      float4 f1 = *(const float4*)(ap + 4);
      unsigned short t8[8] = { f2b(f0.x), f2b(f0.y), f2b(f0.z), f2b(f0.w),
                               f2b(f1.x), f2b(f1.y), f2b(f1.z), f2b(f1.w) };
      *(uint4*)&sAB[rr * 32 + c8] = *(const uint4*)t8;
      uint4 vb = *(const uint4*)(Wt + (size_t)(n0 + rr) * 768 + k0 + c8);
      *(uint4*)&sAB[4096 + rr * 32 + c8] = vb;
    }
    __syncthreads();
    bf16x8 af[4], bfr[4];
    #pragma unroll
    for (int i = 0; i < 4; ++i)
      af[i] = *(const bf16x8*)&sAB[(wr * 64 + i * 16 + lane16) * 32 + quad * 8];
    #pragma unroll
    for (int j = 0; j < 4; ++j)
      bfr[j] = *(const bf16x8*)&sAB[4096 + (wc * 64 + j * 16 + lane16) * 32 + quad * 8];
    #pragma unroll
    for (int i = 0; i < 4; ++i)
      #pragma unroll
      for (int j = 0; j < 4; ++j)
        acc[i][j] = __builtin_amdgcn_mfma_f32_16x16x32_bf16(af[i], bfr[j], acc[i][j], 0, 0, 0);
    __syncthreads();
  }

  #pragma unroll
  for (int j = 0; j < 4; ++j) {
    const int col = n0 + wc * 64 + j * 16 + lane16;
    const float bv = bias[col];
    #pragma unroll
    for (int i = 0; i < 4; ++i) {
      const int r0 = row0 + wr * 64 + i * 16 + quad * 4;
      #pragma unroll
      for (int r = 0; r < 4; ++r)
        if (r0 + r < Mrows)
          C[(size_t)(r0 + r) * 768 + col] = acc[i][j][r] + bv;
    }
  }
}

// fused QKV: blockIdx.x in [0,18): mat = bx/6 (0->K from x, 1->V from x, 2->Q from y)
__global__ __launch_bounds__(256, 2) void qkv_gemm(
    const float* __restrict__ X, const float* __restrict__ Y,
    const unsigned short* __restrict__ WkT, const unsigned short* __restrict__ WvT,
    const unsigned short* __restrict__ WqT,
    const float* __restrict__ bk, const float* __restrict__ bv, const float* __restrict__ bq,
    float* __restrict__ K, float* __restrict__ V, float* __restrict__ Q,
    const int Mrows) {
  __shared__ unsigned short sAB[8192];   // As[128][32] | Bs[128][32] (bf16)
  const int mat = blockIdx.x / 6;
  const int n0 = (blockIdx.x % 6) * 128;
  const float* A = (mat == 2) ? Y : X;
  const unsigned short* Wt = (mat == 0) ? WkT : (mat == 1) ? WvT : WqT;
  const float* bias = (mat == 0) ? bk : (mat == 1) ? bv : bq;
  float* C = (mat == 0) ? K : (mat == 1) ? V : Q;
  gemm_body(A, Wt, bias, C, blockIdx.y * 128, n0, Mrows, sAB);
}

__global__ __launch_bounds__(256, 2) void gemm_bt(
    const float* __restrict__ A, const unsigned short* __restrict__ Wt,
    const float* __restrict__ bias, float* __restrict__ C, const int Mrows) {
  __shared__ unsigned short sAB[8192];
  gemm_body(A, Wt, bias, C, blockIdx.y * 128, blockIdx.x * 128, Mrows, sAB);
}

// -------- CLS token: full attention over 197 keys. 1 block per (b,h) --------
__global__ void cls_attn(const float* __restrict__ Q,
                         const float* __restrict__ K,
                         const float* __restrict__ V,
                         float* __restrict__ ATT) {
  __shared__ float q[64];
  __shared__ float attn[256];
  __shared__ float red[8];
  const int tid = threadIdx.x, l = tid & 63, w = tid >> 6;
  const int b = blockIdx.x / 12, h = blockIdx.x % 12;
  const size_t rowbase = ((size_t)b * NTOK) * 768 + h * 64;

  if (tid < 64) q[tid] = Q[rowbase + tid];
  __syncthreads();

  float d = -3e38f;
  if (tid < NTOK) {
    const float4* Kp = (const float4*)(K + rowbase + (size_t)tid * 768);
    float s = 0.f;
    #pragma unroll
    for (int u = 0; u < 16; ++u) {
      float4 kk = Kp[u];
      s += q[u * 4 + 0] * kk.x + q[u * 4 + 1] * kk.y
         + q[u * 4 + 2] * kk.z + q[u * 4 + 3] * kk.w;
    }
    d = s * 0.125f;
  }
  float m = d;
  #pragma unroll
  for (int off = 32; off; off >>= 1) m = fmaxf(m, __shfl_xor(m, off, 64));
  if (l == 0) red[w] = m;
  __syncthreads();
  const float M = fmaxf(fmaxf(red[0], red[1]), fmaxf(red[2], red[3]));
  float e = (tid < NTOK) ? __expf(d - M) : 0.f;
  float ssum = e;
  #pragma unroll
  for (int off = 32; off; off >>= 1) ssum += __shfl_xor(ssum, off, 64);
  if (l == 0) red[4 + w] = ssum;
  __syncthreads();
  const float S = red[4] + red[5] + red[6] + red[7];
  attn[tid] = e / S;
  __syncthreads();
  if (tid < 64) {
    float o = 0.f;
    for (int j = 0; j < NTOK; ++j)
      o += attn[j] * V[rowbase + (size_t)j * 768 + tid];
    ATT[rowbase + tid] = o;
  }
}

// -------- patch tokens: 3x3 local attention. 1 wave per (b,p,h) --------
__global__ void patch_attn(const float* __restrict__ Q,
                           const float* __restrict__ K,
                           const float* __restrict__ V,
                           float* __restrict__ ATT) {
  const int wgid = blockIdx.x * 4 + (threadIdx.x >> 6);
  const int l = threadIdx.x & 63;
  const int h = wgid % 12;
  const int t2 = wgid / 12;
  const int p = t2 % 196;
  const int b = t2 / 196;
  const int r = p / 14, c = p % 14;
  const size_t base = ((size_t)b * NTOK) * 768 + h * 64 + l;

  const float qd = Q[base + (size_t)(p + 1) * 768];

  float s[9];
  int tok[9];
  #pragma unroll
  for (int jj = 0; jj < 9; ++jj) {
    const int nr = r + jj / 3 - 1, nc = c + jj % 3 - 1;
    const bool ok = ((unsigned)nr < 14u) && ((unsigned)nc < 14u);
    tok[jj] = ok ? (1 + nr * 14 + nc) : (p + 1);
    float d = qd * K[base + (size_t)tok[jj] * 768];
    #pragma unroll
    for (int off = 32; off; off >>= 1) d += __shfl_xor(d, off, 64);
    s[jj] = ok ? d * 0.125f : -3e38f;
  }
  float m = s[0];
  #pragma unroll
  for (int jj = 1; jj < 9; ++jj) m = fmaxf(m, s[jj]);
  float sum = 0.f;
  #pragma unroll
  for (int jj = 0; jj < 9; ++jj) { s[jj] = __expf(s[jj] - m); sum += s[jj]; }
  const float inv = 1.f / sum;
  float o = 0.f;
  #pragma unroll
  for (int jj = 0; jj < 9; ++jj) o += s[jj] * V[base + (size_t)tok[jj] * 768];
  ATT[base + (size_t)(p + 1) * 768] = o * inv;
}

extern "C" void kernel_launch(void* const* d_in, const int* in_sizes, int n_in,
                              void* d_out, int out_size, void* d_ws, size_t ws_size,
                              hipStream_t stream) {
  const float* x  = (const float*)d_in[0];
  const float* y  = (const float*)d_in[1];
  const float* Wq = (const float*)d_in[2];
  const float* bq = (const float*)d_in[3];
  const float* Wk = (const float*)d_in[4];
  const float* bk = (const float*)d_in[5];
  const float* Wv = (const float*)d_in[6];
  const float* bv = (const float*)d_in[7];
  const float* Wo = (const float*)d_in[8];
  const float* bo = (const float*)d_in[9];
  float* out = (float*)d_out;

  unsigned short* WqT = (unsigned short*)d_ws;
  unsigned short* WkT = WqT + W_ELEMS;
  unsigned short* WvT = WkT + W_ELEMS;
  unsigned short* WoT = WvT + W_ELEMS;

  transpose768x4<<<dim3(2304, 4), 256, 0, stream>>>(Wq, Wk, Wv, Wo, WqT, WkT, WvT, WoT);

  const size_t need_full = 4 * W_ELEMS * sizeof(unsigned short)
                         + 3 * BUF_ELEMS_FULL * sizeof(float);   // ~237 MB

  if (ws_size >= need_full) {
    // ---- full-batch path: 4 more launches total ----
    float* Kc = (float*)(WoT + W_ELEMS);
    float* Vc = Kc + BUF_ELEMS_FULL;
    float* Qc = Vc + BUF_ELEMS_FULL;   // attention output aliases Qc

    qkv_gemm<<<dim3(18, MTILES_FULL), 256, 0, stream>>>(
        x, y, WkT, WvT, WqT, bk, bv, bq, Kc, Vc, Qc, MROWS);
    cls_attn<<<BATCH * 12, 256, 0, stream>>>(Qc, Kc, Vc, Qc);
    patch_attn<<<(BATCH * 196 * 12) / 4, 256, 0, stream>>>(Qc, Kc, Vc, Qc);
    gemm_bt<<<dim3(6, MTILES_FULL), 256, 0, stream>>>(Qc, WoT, bo, out, MROWS);
  } else {
    // ---- fallback: old 16-chunk flow (ws ~19 MB) ----
    float* Kc = (float*)(WoT + W_ELEMS);
    float* Vc = Kc + BUF_ELEMS_CHUNK;
    float* Qc = Vc + BUF_ELEMS_CHUNK;

    for (int c = 0; c < NCHUNK; ++c) {
      const float* xc = x + (size_t)c * BUF_ELEMS_CHUNK;
      const float* yc = y + (size_t)c * BUF_ELEMS_CHUNK;
      qkv_gemm<<<dim3(18, MTILES_CHUNK), 256, 0, stream>>>(
          xc, yc, WkT, WvT, WqT, bk, bv, bq, Kc, Vc, Qc, MC_CHUNK);
      cls_attn<<<CHUNK_B * 12, 256, 0, stream>>>(Qc, Kc, Vc, Qc);
      patch_attn<<<(CHUNK_B * 196 * 12) / 4, 256, 0, stream>>>(Qc, Kc, Vc, Qc);
      gemm_bt<<<dim3(6, MTILES_CHUNK), 256, 0, stream>>>(Qc, WoT, bo,
                                                         out + (size_t)c * BUF_ELEMS_CHUNK, MC_CHUNK);
    }
  }
}

// Round 2
// 752.823 us; speedup vs baseline: 3.6857x; 1.0216x over previous
//
#include <hip/hip_runtime.h>

// CrossAttention: x_qkv->K,V ; y_q->Q ; CLS full attn + patch 3x3 local attn ; @Wo+bo
// I/O fp32. Internals: bf16 MFMA GEMMs.
//
// THIS VERSION (vs round-1):
//  - X pre-converted to bf16 once (cvt8). K/V GEMMs read bf16 A directly.
//  - GEMM staging for bf16 operands uses __builtin_amdgcn_global_load_lds
//    width=16 (async global->LDS, no VGPR round-trip, no f2b in the loop).
//    LDS layout is the same linear ch*16 order the old staging produced.
//  - Attention writes output as bf16 (same RNE rounding the O-GEMM staging
//    applied before -> bit-identical O-GEMM inputs). ATTb aliases dead Xb.
//  - Q GEMM keeps the fp32->bf16 staging path (Y-bf16 doesn't fit in ws).
// Workspace: 4.7 MB weights + 38.7 MB Xb/ATTb + 232.4 MB K,V,Q = 275.8 MB.

typedef __bf16 bf16x8 __attribute__((ext_vector_type(8)));
typedef float f32x4 __attribute__((ext_vector_type(4)));

#define NTOK 197
#define BATCH 128
#define MROWS (BATCH * NTOK)            // 25216, divisible by 128
#define MTILES_FULL (MROWS / 128)       // 197
#define W_ELEMS ((size_t)768 * 768)
#define BUF_ELEMS_FULL ((size_t)MROWS * 768)

// fallback chunked config (old behavior, small-ws safety net)
#define CHUNK_B 8
#define NCHUNK 16
#define MC_CHUNK (CHUNK_B * NTOK)       // 1576
#define MTILES_CHUNK 13
#define BUF_ELEMS_CHUNK ((size_t)MC_CHUNK * 768)

__device__ __forceinline__ unsigned short f2b(float f) {
  unsigned int x = __float_as_uint(f);
  x += 0x7fff + ((x >> 16) & 1);          // RNE
  return (unsigned short)(x >> 16);
}

#define GLOAD_LDS16(gp, lp)                                                   \
  __builtin_amdgcn_global_load_lds(                                           \
      (const __attribute__((address_space(1))) void*)(gp),                    \
      (__attribute__((address_space(3))) void*)(lp), 16, 0, 0)

// -------- weight transpose+convert: Wt[n*768+k] = bf16(W[k*768+n]) --------
__global__ void transpose768x4(const float* __restrict__ s0, const float* __restrict__ s1,
                               const float* __restrict__ s2, const float* __restrict__ s3,
                               unsigned short* __restrict__ d0, unsigned short* __restrict__ d1,
                               unsigned short* __restrict__ d2, unsigned short* __restrict__ d3) {
  const float* src;
  unsigned short* dst;
  switch (blockIdx.y) {
    case 0: src = s0; dst = d0; break;
    case 1: src = s1; dst = d1; break;
    case 2: src = s2; dst = d2; break;
    default: src = s3; dst = d3; break;
  }
  int idx = blockIdx.x * 256 + threadIdx.x;   // 589824 total
  int n = idx / 768, k = idx % 768;
  dst[idx] = f2b(src[k * 768 + n]);
}

// -------- fp32 -> bf16 bulk convert, 8 elems/thread --------
__global__ void cvt8(const float* __restrict__ src, unsigned short* __restrict__ dst,
                     const int n8) {
  int i = blockIdx.x * 256 + threadIdx.x;
  if (i >= n8) return;
  const float4* p = (const float4*)(src + (size_t)i * 8);
  float4 f0 = p[0], f1 = p[1];
  unsigned short t8[8] = { f2b(f0.x), f2b(f0.y), f2b(f0.z), f2b(f0.w),
                           f2b(f1.x), f2b(f1.y), f2b(f1.z), f2b(f1.w) };
  *(uint4*)(dst + (size_t)i * 8) = *(const uint4*)t8;
}

// -------- GEMM compute core (shared by both staging variants) --------
__device__ __forceinline__ void gemm_compute_tile(
    unsigned short* sAB, f32x4 (&acc)[4][4],
    const int wr, const int wc, const int lane16, const int quad) {
  bf16x8 af[4], bfr[4];
  #pragma unroll
  for (int i = 0; i < 4; ++i)
    af[i] = *(const bf16x8*)&sAB[(wr * 64 + i * 16 + lane16) * 32 + quad * 8];
  #pragma unroll
  for (int j = 0; j < 4; ++j)
    bfr[j] = *(const bf16x8*)&sAB[4096 + (wc * 64 + j * 16 + lane16) * 32 + quad * 8];
  #pragma unroll
  for (int i = 0; i < 4; ++i)
    #pragma unroll
    for (int j = 0; j < 4; ++j)
      acc[i][j] = __builtin_amdgcn_mfma_f32_16x16x32_bf16(af[i], bfr[j], acc[i][j], 0, 0, 0);
}

__device__ __forceinline__ void gemm_epilogue(
    f32x4 (&acc)[4][4], const float* __restrict__ bias, float* __restrict__ C,
    const int row0, const int n0, const int Mrows,
    const int wr, const int wc, const int lane16, const int quad) {
  #pragma unroll
  for (int j = 0; j < 4; ++j) {
    const int col = n0 + wc * 64 + j * 16 + lane16;
    const float bv = bias[col];
    #pragma unroll
    for (int i = 0; i < 4; ++i) {
      const int r0 = row0 + wr * 64 + i * 16 + quad * 4;
      #pragma unroll
      for (int r = 0; r < 4; ++r)
        if (r0 + r < Mrows)
          C[(size_t)(r0 + r) * 768 + col] = acc[i][j][r] + bv;
    }
  }
}

// -------- GEMM body, A fp32 (convert during staging) --------
__device__ __forceinline__ void gemm_body_f32A(
    const float* __restrict__ A, const unsigned short* __restrict__ Wt,
    const float* __restrict__ bias, float* __restrict__ C,
    const int row0, const int n0, const int Mrows, unsigned short* sAB) {
  const int tid = threadIdx.x;
  const int l = tid & 63, w = tid >> 6;
  const int wr = w >> 1, wc = w & 1;
  const int lane16 = l & 15, quad = l >> 4;

  f32x4 acc[4][4] = {};

  for (int kt = 0; kt < 24; ++kt) {
    const int k0 = kt * 32;
    #pragma unroll
    for (int i = 0; i < 2; ++i) {
      const int ch = i * 256 + tid;          // 0..511
      const int rr = ch >> 2;
      const int c8 = (ch & 3) * 8;
      int ra = row0 + rr; if (ra > Mrows - 1) ra = Mrows - 1;
      const float* ap = A + (size_t)ra * 768 + k0 + c8;
      float4 f0 = *(const float4*)ap;
      float4 f1 = *(const float4*)(ap + 4);
      unsigned short t8[8] = { f2b(f0.x), f2b(f0.y), f2b(f0.z), f2b(f0.w),
                               f2b(f1.x), f2b(f1.y), f2b(f1.z), f2b(f1.w) };
      *(uint4*)&sAB[rr * 32 + c8] = *(const uint4*)t8;
      uint4 vb = *(const uint4*)(Wt + (size_t)(n0 + rr) * 768 + k0 + c8);
      *(uint4*)&sAB[4096 + rr * 32 + c8] = vb;
    }
    __syncthreads();
    gemm_compute_tile(sAB, acc, wr, wc, lane16, quad);
    __syncthreads();
  }
  gemm_epilogue(acc, bias, C, row0, n0, Mrows, wr, wc, lane16, quad);
}

// -------- GEMM body, A bf16 (async global_load_lds staging, width=16) -----
__device__ __forceinline__ void gemm_body_bf16A(
    const unsigned short* __restrict__ A, const unsigned short* __restrict__ Wt,
    const float* __restrict__ bias, float* __restrict__ C,
    const int row0, const int n0, const int Mrows, unsigned short* sAB) {
  const int tid = threadIdx.x;
  const int l = tid & 63, w = tid >> 6;
  const int wr = w >> 1, wc = w & 1;
  const int lane16 = l & 15, quad = l >> 4;

  // chunk ch in [0,512): 16 B each, LDS linear at byte ch*16.
  const int ch0 = tid, ch1 = 256 + tid;
  const int rr0 = ch0 >> 2, c80 = (ch0 & 3) * 8;
  const int rr1 = ch1 >> 2, c81 = (ch1 & 3) * 8;
  int ra0 = row0 + rr0; if (ra0 > Mrows - 1) ra0 = Mrows - 1;
  int ra1 = row0 + rr1; if (ra1 > Mrows - 1) ra1 = Mrows - 1;
  const unsigned short* a0 = A + (size_t)ra0 * 768 + c80;
  const unsigned short* a1 = A + (size_t)ra1 * 768 + c81;
  const unsigned short* b0 = Wt + (size_t)(n0 + rr0) * 768 + c80;
  const unsigned short* b1 = Wt + (size_t)(n0 + rr1) * 768 + c81;
  // wave-uniform LDS bases (HW writes lane l at base + l*16)
  unsigned short* lA0 = sAB + (size_t)(tid & 192) * 8;
  unsigned short* lA1 = sAB + (size_t)(256 + (tid & 192)) * 8;
  unsigned short* lB0 = sAB + 4096 + (size_t)(tid & 192) * 8;
  unsigned short* lB1 = sAB + 4096 + (size_t)(256 + (tid & 192)) * 8;

  f32x4 acc[4][4] = {};

  for (int kt = 0; kt < 24; ++kt) {
    const int k0 = kt * 32;
    GLOAD_LDS16(a0 + k0, lA0);
    GLOAD_LDS16(a1 + k0, lA1);
    GLOAD_LDS16(b0 + k0, lB0);
    GLOAD_LDS16(b1 + k0, lB1);
    __syncthreads();
    gemm_compute_tile(sAB, acc, wr, wc, lane16, quad);
    __syncthreads();
  }
  gemm_epilogue(acc, bias, C, row0, n0, Mrows, wr, wc, lane16, quad);
}

// fused QKV (full-batch): bx/6 -> 0:K(Xb) 1:V(Xb) 2:Q(Y, f32 staging)
__global__ __launch_bounds__(256, 2) void qkv_gemm_full(
    const unsigned short* __restrict__ Xb, const float* __restrict__ Y,
    const unsigned short* __restrict__ WkT, const unsigned short* __restrict__ WvT,
    const unsigned short* __restrict__ WqT,
    const float* __restrict__ bk, const float* __restrict__ bv, const float* __restrict__ bq,
    float* __restrict__ K, float* __restrict__ V, float* __restrict__ Q) {
  __shared__ unsigned short sAB[8192];
  const int mat = blockIdx.x / 6;
  const int n0 = (blockIdx.x % 6) * 128;
  const int row0 = blockIdx.y * 128;
  if (mat == 2) {
    gemm_body_f32A(Y, WqT, bq, Q, row0, n0, MROWS, sAB);
  } else if (mat == 0) {
    gemm_body_bf16A(Xb, WkT, bk, K, row0, n0, MROWS, sAB);
  } else {
    gemm_body_bf16A(Xb, WvT, bv, V, row0, n0, MROWS, sAB);
  }
}

// O-projection GEMM (full-batch): A = bf16 attention output
__global__ __launch_bounds__(256, 2) void o_gemm(
    const unsigned short* __restrict__ ATTb, const unsigned short* __restrict__ WoT,
    const float* __restrict__ bo, float* __restrict__ C) {
  __shared__ unsigned short sAB[8192];
  gemm_body_bf16A(ATTb, WoT, bo, C, blockIdx.y * 128, blockIdx.x * 128, MROWS, sAB);
}

// fallback kernels (chunked path, fp32 A everywhere)
__global__ __launch_bounds__(256, 2) void qkv_gemm(
    const float* __restrict__ X, const float* __restrict__ Y,
    const unsigned short* __restrict__ WkT, const unsigned short* __restrict__ WvT,
    const unsigned short* __restrict__ WqT,
    const float* __restrict__ bk, const float* __restrict__ bv, const float* __restrict__ bq,
    float* __restrict__ K, float* __restrict__ V, float* __restrict__ Q,
    const int Mrows) {
  __shared__ unsigned short sAB[8192];
  const int mat = blockIdx.x / 6;
  const int n0 = (blockIdx.x % 6) * 128;
  const float* A = (mat == 2) ? Y : X;
  const unsigned short* Wt = (mat == 0) ? WkT : (mat == 1) ? WvT : WqT;
  const float* bias = (mat == 0) ? bk : (mat == 1) ? bv : bq;
  float* C = (mat == 0) ? K : (mat == 1) ? V : Q;
  gemm_body_f32A(A, Wt, bias, C, blockIdx.y * 128, n0, Mrows, sAB);
}

__global__ __launch_bounds__(256, 2) void gemm_bt(
    const float* __restrict__ A, const unsigned short* __restrict__ Wt,
    const float* __restrict__ bias, float* __restrict__ C, const int Mrows) {
  __shared__ unsigned short sAB[8192];
  gemm_body_f32A(A, Wt, bias, C, blockIdx.y * 128, blockIdx.x * 128, Mrows, sAB);
}

// -------- CLS token: full attention over 197 keys. 1 block per (b,h) --------
__device__ __forceinline__ float cls_attn_body(const float* __restrict__ Q,
                                               const float* __restrict__ K,
                                               const float* __restrict__ V,
                                               const size_t rowbase,
                                               float* q, float* attn, float* red) {
  const int tid = threadIdx.x, l = tid & 63, w = tid >> 6;
  if (tid < 64) q[tid] = Q[rowbase + tid];
  __syncthreads();

  float d = -3e38f;
  if (tid < NTOK) {
    const float4* Kp = (const float4*)(K + rowbase + (size_t)tid * 768);
    float s = 0.f;
    #pragma unroll
    for (int u = 0; u < 16; ++u) {
      float4 kk = Kp[u];
      s += q[u * 4 + 0] * kk.x + q[u * 4 + 1] * kk.y
         + q[u * 4 + 2] * kk.z + q[u * 4 + 3] * kk.w;
    }
    d = s * 0.125f;
  }
  float m = d;
  #pragma unroll
  for (int off = 32; off; off >>= 1) m = fmaxf(m, __shfl_xor(m, off, 64));
  if (l == 0) red[w] = m;
  __syncthreads();
  const float M = fmaxf(fmaxf(red[0], red[1]), fmaxf(red[2], red[3]));
  float e = (tid < NTOK) ? __expf(d - M) : 0.f;
  float ssum = e;
  #pragma unroll
  for (int off = 32; off; off >>= 1) ssum += __shfl_xor(ssum, off, 64);
  if (l == 0) red[4 + w] = ssum;
  __syncthreads();
  const float S = red[4] + red[5] + red[6] + red[7];
  attn[tid] = e / S;
  __syncthreads();
  float o = 0.f;
  if (tid < 64) {
    for (int j = 0; j < NTOK; ++j)
      o += attn[j] * V[rowbase + (size_t)j * 768 + tid];
  }
  return o;
}

__global__ void cls_attn_b(const float* __restrict__ Q, const float* __restrict__ K,
                           const float* __restrict__ V, unsigned short* __restrict__ ATT) {
  __shared__ float q[64];
  __shared__ float attn[256];
  __shared__ float red[8];
  const int b = blockIdx.x / 12, h = blockIdx.x % 12;
  const size_t rowbase = ((size_t)b * NTOK) * 768 + h * 64;
  float o = cls_attn_body(Q, K, V, rowbase, q, attn, red);
  if (threadIdx.x < 64) ATT[rowbase + threadIdx.x] = f2b(o);
}

__global__ void cls_attn(const float* __restrict__ Q, const float* __restrict__ K,
                         const float* __restrict__ V, float* __restrict__ ATT) {
  __shared__ float q[64];
  __shared__ float attn[256];
  __shared__ float red[8];
  const int b = blockIdx.x / 12, h = blockIdx.x % 12;
  const size_t rowbase = ((size_t)b * NTOK) * 768 + h * 64;
  float o = cls_attn_body(Q, K, V, rowbase, q, attn, red);
  if (threadIdx.x < 64) ATT[rowbase + threadIdx.x] = o;
}

// -------- patch tokens: 3x3 local attention. 1 wave per (b,p,h) --------
__device__ __forceinline__ float patch_attn_body(const float* __restrict__ Q,
                                                 const float* __restrict__ K,
                                                 const float* __restrict__ V,
                                                 const size_t base, const int p,
                                                 const int r, const int c) {
  const float qd = Q[base + (size_t)(p + 1) * 768];

  float s[9];
  int tok[9];
  #pragma unroll
  for (int jj = 0; jj < 9; ++jj) {
    const int nr = r + jj / 3 - 1, nc = c + jj % 3 - 1;
    const bool ok = ((unsigned)nr < 14u) && ((unsigned)nc < 14u);
    tok[jj] = ok ? (1 + nr * 14 + nc) : (p + 1);
    float d = qd * K[base + (size_t)tok[jj] * 768];
    #pragma unroll
    for (int off = 32; off; off >>= 1) d += __shfl_xor(d, off, 64);
    s[jj] = ok ? d * 0.125f : -3e38f;
  }
  float m = s[0];
  #pragma unroll
  for (int jj = 1; jj < 9; ++jj) m = fmaxf(m, s[jj]);
  float sum = 0.f;
  #pragma unroll
  for (int jj = 0; jj < 9; ++jj) { s[jj] = __expf(s[jj] - m); sum += s[jj]; }
  const float inv = 1.f / sum;
  float o = 0.f;
  #pragma unroll
  for (int jj = 0; jj < 9; ++jj) o += s[jj] * V[base + (size_t)tok[jj] * 768];
  return o * inv;
}

__global__ void patch_attn_b(const float* __restrict__ Q, const float* __restrict__ K,
                             const float* __restrict__ V, unsigned short* __restrict__ ATT) {
  const int wgid = blockIdx.x * 4 + (threadIdx.x >> 6);
  const int l = threadIdx.x & 63;
  const int h = wgid % 12;
  const int t2 = wgid / 12;
  const int p = t2 % 196;
  const int b = t2 / 196;
  const int r = p / 14, c = p % 14;
  const size_t base = ((size_t)b * NTOK) * 768 + h * 64 + l;
  float o = patch_attn_body(Q, K, V, base, p, r, c);
  ATT[base + (size_t)(p + 1) * 768] = f2b(o);
}

__global__ void patch_attn(const float* __restrict__ Q, const float* __restrict__ K,
                           const float* __restrict__ V, float* __restrict__ ATT) {
  const int wgid = blockIdx.x * 4 + (threadIdx.x >> 6);
  const int l = threadIdx.x & 63;
  const int h = wgid % 12;
  const int t2 = wgid / 12;
  const int p = t2 % 196;
  const int b = t2 / 196;
  const int r = p / 14, c = p % 14;
  const size_t base = ((size_t)b * NTOK) * 768 + h * 64 + l;
  float o = patch_attn_body(Q, K, V, base, p, r, c);
  ATT[base + (size_t)(p + 1) * 768] = o;
}

extern "C" void kernel_launch(void* const* d_in, const int* in_sizes, int n_in,
                              void* d_out, int out_size, void* d_ws, size_t ws_size,
                              hipStream_t stream) {
  const float* x  = (const float*)d_in[0];
  const float* y  = (const float*)d_in[1];
  const float* Wq = (const float*)d_in[2];
  const float* bq = (const float*)d_in[3];
  const float* Wk = (const float*)d_in[4];
  const float* bk = (const float*)d_in[5];
  const float* Wv = (const float*)d_in[6];
  const float* bv = (const float*)d_in[7];
  const float* Wo = (const float*)d_in[8];
  const float* bo = (const float*)d_in[9];
  float* out = (float*)d_out;

  unsigned short* WqT = (unsigned short*)d_ws;
  unsigned short* WkT = WqT + W_ELEMS;
  unsigned short* WvT = WkT + W_ELEMS;
  unsigned short* WoT = WvT + W_ELEMS;

  transpose768x4<<<dim3(2304, 4), 256, 0, stream>>>(Wq, Wk, Wv, Wo, WqT, WkT, WvT, WoT);

  const size_t need_full = 4 * W_ELEMS * sizeof(unsigned short)
                         + BUF_ELEMS_FULL * sizeof(unsigned short)   // Xb / ATTb
                         + 3 * BUF_ELEMS_FULL * sizeof(float);       // K,V,Q
  if (ws_size >= need_full) {
    // ---- full-batch path: 6 launches ----
    unsigned short* Xb = WoT + W_ELEMS;          // aliased by ATTb after qkv
    unsigned short* ATTb = Xb;
    float* Kc = (float*)(Xb + BUF_ELEMS_FULL);
    float* Vc = Kc + BUF_ELEMS_FULL;
    float* Qc = Vc + BUF_ELEMS_FULL;

    const int n8 = (int)(BUF_ELEMS_FULL / 8);    // 2,420,736 (exact, /256 = 9456)
    cvt8<<<n8 / 256, 256, 0, stream>>>(x, Xb, n8);

    qkv_gemm_full<<<dim3(18, MTILES_FULL), 256, 0, stream>>>(
        Xb, y, WkT, WvT, WqT, bk, bv, bq, Kc, Vc, Qc);
    cls_attn_b<<<BATCH * 12, 256, 0, stream>>>(Qc, Kc, Vc, ATTb);
    patch_attn_b<<<(BATCH * 196 * 12) / 4, 256, 0, stream>>>(Qc, Kc, Vc, ATTb);
    o_gemm<<<dim3(6, MTILES_FULL), 256, 0, stream>>>(ATTb, WoT, bo, out);
  } else {
    // ---- fallback: old 16-chunk flow (ws ~19 MB) ----
    float* Kc = (float*)(WoT + W_ELEMS);
    float* Vc = Kc + BUF_ELEMS_CHUNK;
    float* Qc = Vc + BUF_ELEMS_CHUNK;

    for (int c = 0; c < NCHUNK; ++c) {
      const float* xc = x + (size_t)c * BUF_ELEMS_CHUNK;
      const float* yc = y + (size_t)c * BUF_ELEMS_CHUNK;
      qkv_gemm<<<dim3(18, MTILES_CHUNK), 256, 0, stream>>>(
          xc, yc, WkT, WvT, WqT, bk, bv, bq, Kc, Vc, Qc, MC_CHUNK);
      cls_attn<<<CHUNK_B * 12, 256, 0, stream>>>(Qc, Kc, Vc, Qc);
      patch_attn<<<(CHUNK_B * 196 * 12) / 4, 256, 0, stream>>>(Qc, Kc, Vc, Qc);
      gemm_bt<<<dim3(6, MTILES_CHUNK), 256, 0, stream>>>(Qc, WoT, bo,
                                                         out + (size_t)c * BUF_ELEMS_CHUNK, MC_CHUNK);
    }
  }
}

// Round 3
// 656.470 us; speedup vs baseline: 4.2266x; 1.1468x over previous
//
#include <hip/hip_runtime.h>

// CrossAttention: x_qkv->K,V ; y_q->Q ; CLS full attn + patch 3x3 local attn ; @Wo+bo
// I/O fp32. Internals: bf16 MFMA GEMMs.
//
// THIS VERSION (vs round-2):
//  - KV-fused GEMM: one block stages the A-tile once and runs both Wk and Wv
//    B-tiles -> 32 MFMA per barrier (2x compute per stall), halves A traffic.
//  - XCD-chunked bijective block swizzle (m204 form) on all GEMMs: blocks
//    sharing an A row-panel land on the same XCD -> A-panels L2-resident.
//  - 2-phase double-buffered staging (T3-minimal): stage tile t+1 before
//    computing tile t; one __syncthreads per K-step; loads fly under MFMA.
//  - Q GEMM: reg-staged fp32 A (load-early/convert-late) + gload_lds B, dbuf.
// Workspace layout unchanged: weights 4.7MB + Xb/ATTb 38.7MB + K,V,Q fp32.

typedef __bf16 bf16x8 __attribute__((ext_vector_type(8)));
typedef float f32x4 __attribute__((ext_vector_type(4)));

#define NTOK 197
#define BATCH 128
#define MROWS (BATCH * NTOK)            // 25216, divisible by 128
#define MTILES_FULL (MROWS / 128)       // 197
#define NB_FULL (6 * MTILES_FULL)       // 1182 blocks per GEMM
#define W_ELEMS ((size_t)768 * 768)
#define BUF_ELEMS_FULL ((size_t)MROWS * 768)

// fallback chunked config (small-ws safety net)
#define CHUNK_B 8
#define NCHUNK 16
#define MC_CHUNK (CHUNK_B * NTOK)       // 1576
#define MTILES_CHUNK 13
#define BUF_ELEMS_CHUNK ((size_t)MC_CHUNK * 768)

__device__ __forceinline__ unsigned short f2b(float f) {
  unsigned int x = __float_as_uint(f);
  x += 0x7fff + ((x >> 16) & 1);          // RNE
  return (unsigned short)(x >> 16);
}

__device__ __forceinline__ uint4 cvt8pack(float4 f0, float4 f1) {
  unsigned short t8[8] = { f2b(f0.x), f2b(f0.y), f2b(f0.z), f2b(f0.w),
                           f2b(f1.x), f2b(f1.y), f2b(f1.z), f2b(f1.w) };
  return *(const uint4*)t8;
}

#define GLOAD_LDS16(gp, lp)                                                   \
  __builtin_amdgcn_global_load_lds(                                           \
      (const __attribute__((address_space(1))) void*)(gp),                    \
      (__attribute__((address_space(3))) void*)(lp), 16, 0, 0)

// bijective XCD-chunk swizzle (m204): consecutive hw-dispatch ids round-robin
// XCDs; remap so each XCD gets a contiguous run of logical tile ids.
__device__ __forceinline__ int xcd_swizzle(int bid, int nb) {
  const int q = nb >> 3, r = nb & 7;
  const int xcd = bid & 7, i = bid >> 3;
  return (xcd < r ? xcd * (q + 1) : r * (q + 1) + (xcd - r) * q) + i;
}

// -------- weight transpose+convert: Wt[n*768+k] = bf16(W[k*768+n]) --------
__global__ void transpose768x4(const float* __restrict__ s0, const float* __restrict__ s1,
                               const float* __restrict__ s2, const float* __restrict__ s3,
                               unsigned short* __restrict__ d0, unsigned short* __restrict__ d1,
                               unsigned short* __restrict__ d2, unsigned short* __restrict__ d3) {
  const float* src;
  unsigned short* dst;
  switch (blockIdx.y) {
    case 0: src = s0; dst = d0; break;
    case 1: src = s1; dst = d1; break;
    case 2: src = s2; dst = d2; break;
    default: src = s3; dst = d3; break;
  }
  int idx = blockIdx.x * 256 + threadIdx.x;   // 589824 total
  int n = idx / 768, k = idx % 768;
  dst[idx] = f2b(src[k * 768 + n]);
}

// -------- fp32 -> bf16 bulk convert, 8 elems/thread --------
__global__ void cvt8(const float* __restrict__ src, unsigned short* __restrict__ dst,
                     const int n8) {
  int i = blockIdx.x * 256 + threadIdx.x;
  if (i >= n8) return;
  const float4* p = (const float4*)(src + (size_t)i * 8);
  *(uint4*)(dst + (size_t)i * 8) = cvt8pack(p[0], p[1]);
}

// -------- MFMA tile helpers (128x128 tile, 4 waves 2x2, 4x4 frags) --------
__device__ __forceinline__ void mfma_tile(const unsigned short* sA, const unsigned short* sB,
                                          f32x4 (&acc)[4][4],
                                          const int wr, const int wc,
                                          const int lane16, const int quad) {
  bf16x8 af[4], bf_[4];
  #pragma unroll
  for (int i = 0; i < 4; ++i)
    af[i] = *(const bf16x8*)&sA[(wr * 64 + i * 16 + lane16) * 32 + quad * 8];
  #pragma unroll
  for (int j = 0; j < 4; ++j)
    bf_[j] = *(const bf16x8*)&sB[(wc * 64 + j * 16 + lane16) * 32 + quad * 8];
  #pragma unroll
  for (int i = 0; i < 4; ++i)
    #pragma unroll
    for (int j = 0; j < 4; ++j)
      acc[i][j] = __builtin_amdgcn_mfma_f32_16x16x32_bf16(af[i], bf_[j], acc[i][j], 0, 0, 0);
}

__device__ __forceinline__ void mfma_tile_kv(const unsigned short* sA,
                                             const unsigned short* sBk,
                                             const unsigned short* sBv,
                                             f32x4 (&aK)[4][4], f32x4 (&aV)[4][4],
                                             const int wr, const int wc,
                                             const int lane16, const int quad) {
  bf16x8 af[4], b1[4], b2[4];
  #pragma unroll
  for (int i = 0; i < 4; ++i)
    af[i] = *(const bf16x8*)&sA[(wr * 64 + i * 16 + lane16) * 32 + quad * 8];
  #pragma unroll
  for (int j = 0; j < 4; ++j) {
    b1[j] = *(const bf16x8*)&sBk[(wc * 64 + j * 16 + lane16) * 32 + quad * 8];
    b2[j] = *(const bf16x8*)&sBv[(wc * 64 + j * 16 + lane16) * 32 + quad * 8];
  }
  #pragma unroll
  for (int i = 0; i < 4; ++i)
    #pragma unroll
    for (int j = 0; j < 4; ++j) {
      aK[i][j] = __builtin_amdgcn_mfma_f32_16x16x32_bf16(af[i], b1[j], aK[i][j], 0, 0, 0);
      aV[i][j] = __builtin_amdgcn_mfma_f32_16x16x32_bf16(af[i], b2[j], aV[i][j], 0, 0, 0);
    }
}

__device__ __forceinline__ void epilogue128(f32x4 (&acc)[4][4], const float* __restrict__ bias,
                                            float* __restrict__ C, const int row0, const int n0,
                                            const int wr, const int wc,
                                            const int lane16, const int quad) {
  #pragma unroll
  for (int j = 0; j < 4; ++j) {
    const int col = n0 + wc * 64 + j * 16 + lane16;
    const float bv = bias[col];
    #pragma unroll
    for (int i = 0; i < 4; ++i) {
      const int r0 = row0 + wr * 64 + i * 16 + quad * 4;
      #pragma unroll
      for (int r = 0; r < 4; ++r)
        C[(size_t)(r0 + r) * 768 + col] = acc[i][j][r] + bv;
    }
  }
}

// -------- KV-fused GEMM: K,V = Xb @ {Wk,Wv}^T + b. 2-phase dbuf staging. ----
__global__ __launch_bounds__(256, 2) void kv_gemm(
    const unsigned short* __restrict__ Xb,
    const unsigned short* __restrict__ WkT, const unsigned short* __restrict__ WvT,
    const float* __restrict__ bk, const float* __restrict__ bv,
    float* __restrict__ K, float* __restrict__ V) {
  __shared__ unsigned short lds[2][3][4096];   // [buf][A,Bk,Bv][128*32]
  const int swz = xcd_swizzle(blockIdx.x, NB_FULL);
  const int by = swz / 6, bx = swz % 6;
  const int row0 = by * 128, n0 = bx * 128;
  const int tid = threadIdx.x;
  const int l = tid & 63, w = tid >> 6;
  const int wr = w >> 1, wc = w & 1;
  const int lane16 = l & 15, quad = l >> 4;
  const int rr = tid >> 2, c8 = (tid & 3) * 8;
  const int wbase = (tid & 192) * 8;           // wave-uniform LDS chunk base

  const unsigned short* a0 = Xb + (size_t)(row0 + rr) * 768 + c8;
  const unsigned short* a1 = a0 + (size_t)64 * 768;
  const unsigned short* k0p = WkT + (size_t)(n0 + rr) * 768 + c8;
  const unsigned short* k1p = k0p + (size_t)64 * 768;
  const unsigned short* v0p = WvT + (size_t)(n0 + rr) * 768 + c8;
  const unsigned short* v1p = v0p + (size_t)64 * 768;

  f32x4 aK[4][4] = {}, aV[4][4] = {};

#define STAGE_KV(B, kt) do { const int ko = (kt) * 32;            \
    GLOAD_LDS16(a0 + ko, &lds[B][0][wbase]);                      \
    GLOAD_LDS16(a1 + ko, &lds[B][0][wbase + 2048]);               \
    GLOAD_LDS16(k0p + ko, &lds[B][1][wbase]);                     \
    GLOAD_LDS16(k1p + ko, &lds[B][1][wbase + 2048]);              \
    GLOAD_LDS16(v0p + ko, &lds[B][2][wbase]);                     \
    GLOAD_LDS16(v1p + ko, &lds[B][2][wbase + 2048]); } while (0)

  STAGE_KV(0, 0);
  __syncthreads();
  for (int kt = 0; kt < 23; ++kt) {
    const int cur = kt & 1;
    STAGE_KV(cur ^ 1, kt + 1);
    mfma_tile_kv(&lds[cur][0][0], &lds[cur][1][0], &lds[cur][2][0],
                 aK, aV, wr, wc, lane16, quad);
    __syncthreads();
  }
  mfma_tile_kv(&lds[1][0][0], &lds[1][1][0], &lds[1][2][0],
               aK, aV, wr, wc, lane16, quad);
#undef STAGE_KV

  epilogue128(aK, bk, K, row0, n0, wr, wc, lane16, quad);
  epilogue128(aV, bv, V, row0, n0, wr, wc, lane16, quad);
}

// -------- O GEMM: out = ATTb @ Wo^T + bo. bf16 A, 2-phase dbuf. ------------
__global__ __launch_bounds__(256, 2) void o_gemm(
    const unsigned short* __restrict__ Ab, const unsigned short* __restrict__ WoT,
    const float* __restrict__ bo, float* __restrict__ C) {
  __shared__ unsigned short lds[2][2][4096];   // [buf][A,B][128*32]
  const int swz = xcd_swizzle(blockIdx.x, NB_FULL);
  const int by = swz / 6, bx = swz % 6;
  const int row0 = by * 128, n0 = bx * 128;
  const int tid = threadIdx.x;
  const int l = tid & 63, w = tid >> 6;
  const int wr = w >> 1, wc = w & 1;
  const int lane16 = l & 15, quad = l >> 4;
  const int rr = tid >> 2, c8 = (tid & 3) * 8;
  const int wbase = (tid & 192) * 8;

  const unsigned short* a0 = Ab + (size_t)(row0 + rr) * 768 + c8;
  const unsigned short* a1 = a0 + (size_t)64 * 768;
  const unsigned short* b0 = WoT + (size_t)(n0 + rr) * 768 + c8;
  const unsigned short* b1 = b0 + (size_t)64 * 768;

  f32x4 acc[4][4] = {};

#define STAGE_O(B, kt) do { const int ko = (kt) * 32;             \
    GLOAD_LDS16(a0 + ko, &lds[B][0][wbase]);                      \
    GLOAD_LDS16(a1 + ko, &lds[B][0][wbase + 2048]);               \
    GLOAD_LDS16(b0 + ko, &lds[B][1][wbase]);                      \
    GLOAD_LDS16(b1 + ko, &lds[B][1][wbase + 2048]); } while (0)

  STAGE_O(0, 0);
  __syncthreads();
  for (int kt = 0; kt < 23; ++kt) {
    const int cur = kt & 1;
    STAGE_O(cur ^ 1, kt + 1);
    mfma_tile(&lds[cur][0][0], &lds[cur][1][0], acc, wr, wc, lane16, quad);
    __syncthreads();
  }
  mfma_tile(&lds[1][0][0], &lds[1][1][0], acc, wr, wc, lane16, quad);
#undef STAGE_O

  epilogue128(acc, bo, C, row0, n0, wr, wc, lane16, quad);
}

// -------- Q GEMM: fp32 A reg-staged (load-early/convert-late), B dbuf. -----
__global__ __launch_bounds__(256, 2) void q_gemm(
    const float* __restrict__ Y, const unsigned short* __restrict__ WqT,
    const float* __restrict__ bq, float* __restrict__ Q) {
  __shared__ unsigned short As[2][4096];
  __shared__ unsigned short Bs[2][4096];
  const int swz = xcd_swizzle(blockIdx.x, NB_FULL);
  const int by = swz / 6, bx = swz % 6;
  const int row0 = by * 128, n0 = bx * 128;
  const int tid = threadIdx.x;
  const int l = tid & 63, w = tid >> 6;
  const int wr = w >> 1, wc = w & 1;
  const int lane16 = l & 15, quad = l >> 4;
  const int rr = tid >> 2, c8 = (tid & 3) * 8;
  const int wbase = (tid & 192) * 8;

  const float* y0 = Y + (size_t)(row0 + rr) * 768 + c8;
  const float* y1 = y0 + (size_t)64 * 768;
  const unsigned short* b0 = WqT + (size_t)(n0 + rr) * 768 + c8;
  const unsigned short* b1 = b0 + (size_t)64 * 768;

  f32x4 acc[4][4] = {};

  // prologue: tile 0
  float4 f0 = *(const float4*)y0, f1 = *(const float4*)(y0 + 4);
  float4 g0 = *(const float4*)y1, g1 = *(const float4*)(y1 + 4);
  GLOAD_LDS16(b0, &Bs[0][wbase]);
  GLOAD_LDS16(b1, &Bs[0][wbase + 2048]);
  *(uint4*)&As[0][rr * 32 + c8] = cvt8pack(f0, f1);
  *(uint4*)&As[0][(64 + rr) * 32 + c8] = cvt8pack(g0, g1);
  __syncthreads();

  for (int kt = 0; kt < 23; ++kt) {
    const int cur = kt & 1, nxt = cur ^ 1;
    const int ko = (kt + 1) * 32;
    f0 = *(const float4*)(y0 + ko); f1 = *(const float4*)(y0 + ko + 4);
    g0 = *(const float4*)(y1 + ko); g1 = *(const float4*)(y1 + ko + 4);
    GLOAD_LDS16(b0 + ko, &Bs[nxt][wbase]);
    GLOAD_LDS16(b1 + ko, &Bs[nxt][wbase + 2048]);
    mfma_tile(&As[cur][0], &Bs[cur][0], acc, wr, wc, lane16, quad);
    *(uint4*)&As[nxt][rr * 32 + c8] = cvt8pack(f0, f1);
    *(uint4*)&As[nxt][(64 + rr) * 32 + c8] = cvt8pack(g0, g1);
    __syncthreads();
  }
  mfma_tile(&As[1][0], &Bs[1][0], acc, wr, wc, lane16, quad);

  epilogue128(acc, bq, Q, row0, n0, wr, wc, lane16, quad);
}

// ==================== fallback (chunked) GEMM bodies ====================
__device__ __forceinline__ void gemm_body_f32A(
    const float* __restrict__ A, const unsigned short* __restrict__ Wt,
    const float* __restrict__ bias, float* __restrict__ C,
    const int row0, const int n0, const int Mrows, unsigned short* sAB) {
  const int tid = threadIdx.x;
  const int l = tid & 63, w = tid >> 6;
  const int wr = w >> 1, wc = w & 1;
  const int lane16 = l & 15, quad = l >> 4;

  f32x4 acc[4][4] = {};

  for (int kt = 0; kt < 24; ++kt) {
    const int k0 = kt * 32;
    #pragma unroll
    for (int i = 0; i < 2; ++i) {
      const int ch = i * 256 + tid;
      const int rr2 = ch >> 2;
      const int c82 = (ch & 3) * 8;
      int ra = row0 + rr2; if (ra > Mrows - 1) ra = Mrows - 1;
      const float* ap = A + (size_t)ra * 768 + k0 + c82;
      float4 q0 = *(const float4*)ap;
      float4 q1 = *(const float4*)(ap + 4);
      *(uint4*)&sAB[rr2 * 32 + c82] = cvt8pack(q0, q1);
      uint4 vb = *(const uint4*)(Wt + (size_t)(n0 + rr2) * 768 + k0 + c82);
      *(uint4*)&sAB[4096 + rr2 * 32 + c82] = vb;
    }
    __syncthreads();
    mfma_tile(sAB, sAB + 4096, acc, wr, wc, lane16, quad);
    __syncthreads();
  }
  #pragma unroll
  for (int j = 0; j < 4; ++j) {
    const int col = n0 + wc * 64 + j * 16 + lane16;
    const float bv = bias[col];
    #pragma unroll
    for (int i = 0; i < 4; ++i) {
      const int r0 = row0 + wr * 64 + i * 16 + quad * 4;
      #pragma unroll
      for (int r = 0; r < 4; ++r)
        if (r0 + r < Mrows)
          C[(size_t)(r0 + r) * 768 + col] = acc[i][j][r] + bv;
    }
  }
}

__global__ __launch_bounds__(256, 2) void qkv_gemm(
    const float* __restrict__ X, const float* __restrict__ Y,
    const unsigned short* __restrict__ WkT, const unsigned short* __restrict__ WvT,
    const unsigned short* __restrict__ WqT,
    const float* __restrict__ bk, const float* __restrict__ bv, const float* __restrict__ bq,
    float* __restrict__ K, float* __restrict__ V, float* __restrict__ Q,
    const int Mrows) {
  __shared__ unsigned short sAB[8192];
  const int mat = blockIdx.x / 6;
  const int n0 = (blockIdx.x % 6) * 128;
  const float* A = (mat == 2) ? Y : X;
  const unsigned short* Wt = (mat == 0) ? WkT : (mat == 1) ? WvT : WqT;
  const float* bias = (mat == 0) ? bk : (mat == 1) ? bv : bq;
  float* C = (mat == 0) ? K : (mat == 1) ? V : Q;
  gemm_body_f32A(A, Wt, bias, C, blockIdx.y * 128, n0, Mrows, sAB);
}

__global__ __launch_bounds__(256, 2) void gemm_bt(
    const float* __restrict__ A, const unsigned short* __restrict__ Wt,
    const float* __restrict__ bias, float* __restrict__ C, const int Mrows) {
  __shared__ unsigned short sAB[8192];
  gemm_body_f32A(A, Wt, bias, C, blockIdx.y * 128, blockIdx.x * 128, Mrows, sAB);
}

// ==================== attention ====================
__device__ __forceinline__ float cls_attn_body(const float* __restrict__ Q,
                                               const float* __restrict__ K,
                                               const float* __restrict__ V,
                                               const size_t rowbase,
                                               float* q, float* attn, float* red) {
  const int tid = threadIdx.x, l = tid & 63, w = tid >> 6;
  if (tid < 64) q[tid] = Q[rowbase + tid];
  __syncthreads();

  float d = -3e38f;
  if (tid < NTOK) {
    const float4* Kp = (const float4*)(K + rowbase + (size_t)tid * 768);
    float s = 0.f;
    #pragma unroll
    for (int u = 0; u < 16; ++u) {
      float4 kk = Kp[u];
      s += q[u * 4 + 0] * kk.x + q[u * 4 + 1] * kk.y
         + q[u * 4 + 2] * kk.z + q[u * 4 + 3] * kk.w;
    }
    d = s * 0.125f;
  }
  float m = d;
  #pragma unroll
  for (int off = 32; off; off >>= 1) m = fmaxf(m, __shfl_xor(m, off, 64));
  if (l == 0) red[w] = m;
  __syncthreads();
  const float M = fmaxf(fmaxf(red[0], red[1]), fmaxf(red[2], red[3]));
  float e = (tid < NTOK) ? __expf(d - M) : 0.f;
  float ssum = e;
  #pragma unroll
  for (int off = 32; off; off >>= 1) ssum += __shfl_xor(ssum, off, 64);
  if (l == 0) red[4 + w] = ssum;
  __syncthreads();
  const float S = red[4] + red[5] + red[6] + red[7];
  attn[tid] = e / S;
  __syncthreads();
  float o = 0.f;
  if (tid < 64) {
    for (int j = 0; j < NTOK; ++j)
      o += attn[j] * V[rowbase + (size_t)j * 768 + tid];
  }
  return o;
}

__global__ void cls_attn_b(const float* __restrict__ Q, const float* __restrict__ K,
                           const float* __restrict__ V, unsigned short* __restrict__ ATT) {
  __shared__ float q[64];
  __shared__ float attn[256];
  __shared__ float red[8];
  const int b = blockIdx.x / 12, h = blockIdx.x % 12;
  const size_t rowbase = ((size_t)b * NTOK) * 768 + h * 64;
  float o = cls_attn_body(Q, K, V, rowbase, q, attn, red);
  if (threadIdx.x < 64) ATT[rowbase + threadIdx.x] = f2b(o);
}

__global__ void cls_attn(const float* __restrict__ Q, const float* __restrict__ K,
                         const float* __restrict__ V, float* __restrict__ ATT) {
  __shared__ float q[64];
  __shared__ float attn[256];
  __shared__ float red[8];
  const int b = blockIdx.x / 12, h = blockIdx.x % 12;
  const size_t rowbase = ((size_t)b * NTOK) * 768 + h * 64;
  float o = cls_attn_body(Q, K, V, rowbase, q, attn, red);
  if (threadIdx.x < 64) ATT[rowbase + threadIdx.x] = o;
}

__device__ __forceinline__ float patch_attn_body(const float* __restrict__ Q,
                                                 const float* __restrict__ K,
                                                 const float* __restrict__ V,
                                                 const size_t base, const int p,
                                                 const int r, const int c) {
  const float qd = Q[base + (size_t)(p + 1) * 768];

  float s[9];
  int tok[9];
  #pragma unroll
  for (int jj = 0; jj < 9; ++jj) {
    const int nr = r + jj / 3 - 1, nc = c + jj % 3 - 1;
    const bool ok = ((unsigned)nr < 14u) && ((unsigned)nc < 14u);
    tok[jj] = ok ? (1 + nr * 14 + nc) : (p + 1);
    float d = qd * K[base + (size_t)tok[jj] * 768];
    #pragma unroll
    for (int off = 32; off; off >>= 1) d += __shfl_xor(d, off, 64);
    s[jj] = ok ? d * 0.125f : -3e38f;
  }
  float m = s[0];
  #pragma unroll
  for (int jj = 1; jj < 9; ++jj) m = fmaxf(m, s[jj]);
  float sum = 0.f;
  #pragma unroll
  for (int jj = 0; jj < 9; ++jj) { s[jj] = __expf(s[jj] - m); sum += s[jj]; }
  const float inv = 1.f / sum;
  float o = 0.f;
  #pragma unroll
  for (int jj = 0; jj < 9; ++jj) o += s[jj] * V[base + (size_t)tok[jj] * 768];
  return o * inv;
}

__global__ void patch_attn_b(const float* __restrict__ Q, const float* __restrict__ K,
                             const float* __restrict__ V, unsigned short* __restrict__ ATT) {
  const int wgid = blockIdx.x * 4 + (threadIdx.x >> 6);
  const int l = threadIdx.x & 63;
  const int h = wgid % 12;
  const int t2 = wgid / 12;
  const int p = t2 % 196;
  const int b = t2 / 196;
  const int r = p / 14, c = p % 14;
  const size_t base = ((size_t)b * NTOK) * 768 + h * 64 + l;
  float o = patch_attn_body(Q, K, V, base, p, r, c);
  ATT[base + (size_t)(p + 1) * 768] = f2b(o);
}

__global__ void patch_attn(const float* __restrict__ Q, const float* __restrict__ K,
                           const float* __restrict__ V, float* __restrict__ ATT) {
  const int wgid = blockIdx.x * 4 + (threadIdx.x >> 6);
  const int l = threadIdx.x & 63;
  const int h = wgid % 12;
  const int t2 = wgid / 12;
  const int p = t2 % 196;
  const int b = t2 / 196;
  const int r = p / 14, c = p % 14;
  const size_t base = ((size_t)b * NTOK) * 768 + h * 64 + l;
  float o = patch_attn_body(Q, K, V, base, p, r, c);
  ATT[base + (size_t)(p + 1) * 768] = o;
}

extern "C" void kernel_launch(void* const* d_in, const int* in_sizes, int n_in,
                              void* d_out, int out_size, void* d_ws, size_t ws_size,
                              hipStream_t stream) {
  const float* x  = (const float*)d_in[0];
  const float* y  = (const float*)d_in[1];
  const float* Wq = (const float*)d_in[2];
  const float* bq = (const float*)d_in[3];
  const float* Wk = (const float*)d_in[4];
  const float* bk = (const float*)d_in[5];
  const float* Wv = (const float*)d_in[6];
  const float* bv = (const float*)d_in[7];
  const float* Wo = (const float*)d_in[8];
  const float* bo = (const float*)d_in[9];
  float* out = (float*)d_out;

  unsigned short* WqT = (unsigned short*)d_ws;
  unsigned short* WkT = WqT + W_ELEMS;
  unsigned short* WvT = WkT + W_ELEMS;
  unsigned short* WoT = WvT + W_ELEMS;

  transpose768x4<<<dim3(2304, 4), 256, 0, stream>>>(Wq, Wk, Wv, Wo, WqT, WkT, WvT, WoT);

  const size_t need_full = 4 * W_ELEMS * sizeof(unsigned short)
                         + BUF_ELEMS_FULL * sizeof(unsigned short)   // Xb / ATTb
                         + 3 * BUF_ELEMS_FULL * sizeof(float);       // K,V,Q
  if (ws_size >= need_full) {
    // ---- full-batch path: 7 launches ----
    unsigned short* Xb = WoT + W_ELEMS;          // aliased by ATTb after qkv
    unsigned short* ATTb = Xb;
    float* Kc = (float*)(Xb + BUF_ELEMS_FULL);
    float* Vc = Kc + BUF_ELEMS_FULL;
    float* Qc = Vc + BUF_ELEMS_FULL;

    const int n8 = (int)(BUF_ELEMS_FULL / 8);
    cvt8<<<n8 / 256, 256, 0, stream>>>(x, Xb, n8);

    kv_gemm<<<NB_FULL, 256, 0, stream>>>(Xb, WkT, WvT, bk, bv, Kc, Vc);
    q_gemm<<<NB_FULL, 256, 0, stream>>>(y, WqT, bq, Qc);
    cls_attn_b<<<BATCH * 12, 256, 0, stream>>>(Qc, Kc, Vc, ATTb);
    patch_attn_b<<<(BATCH * 196 * 12) / 4, 256, 0, stream>>>(Qc, Kc, Vc, ATTb);
    o_gemm<<<NB_FULL, 256, 0, stream>>>(ATTb, WoT, bo, out);
  } else {
    // ---- fallback: old 16-chunk flow (ws ~19 MB) ----
    float* Kc = (float*)(WoT + W_ELEMS);
    float* Vc = Kc + BUF_ELEMS_CHUNK;
    float* Qc = Vc + BUF_ELEMS_CHUNK;

    for (int c = 0; c < NCHUNK; ++c) {
      const float* xc = x + (size_t)c * BUF_ELEMS_CHUNK;
      const float* yc = y + (size_t)c * BUF_ELEMS_CHUNK;
      qkv_gemm<<<dim3(18, MTILES_CHUNK), 256, 0, stream>>>(
          xc, yc, WkT, WvT, WqT, bk, bv, bq, Kc, Vc, Qc, MC_CHUNK);
      cls_attn<<<CHUNK_B * 12, 256, 0, stream>>>(Qc, Kc, Vc, Qc);
      patch_attn<<<(CHUNK_B * 196 * 12) / 4, 256, 0, stream>>>(Qc, Kc, Vc, Qc);
      gemm_bt<<<dim3(6, MTILES_CHUNK), 256, 0, stream>>>(Qc, WoT, bo,
                                                         out + (size_t)c * BUF_ELEMS_CHUNK, MC_CHUNK);
    }
  }
}

// Round 4
// 556.148 us; speedup vs baseline: 4.9891x; 1.1804x over previous
//
#include <hip/hip_runtime.h>

// CrossAttention: x_qkv->K,V ; y_q->Q ; CLS full attn + patch 3x3 local attn ; @Wo+bo
// I/O fp32. Internals: bf16 MFMA GEMMs.
//
// THIS VERSION (vs round-3):
//  - patch_attn rewritten: 1 wave = 4 patches, 16 lanes/patch, lane owns a
//    float4 of d=64. Dot = 4 FMA + 4-step 16-lane shfl reduce (was 1 mul +
//    6-step 64-lane reduce); float4 loads (1/4 the loads + addr math).
//    ~6x fewer VALU instrs/patch-head, 4x fewer waves.
//  - patch grid: h fastest, then patch-quad, then image; bijective XCD
//    chunking (18816 blocks) -> each XCD streams its own 16 images, K/V rows
//    L2-resident across the 108 (9 nbr x 12 head) reuses.
// GEMMs/cls/cvt unchanged from round-3 (KV-fused, dbuf, gload_lds, swizzle).

typedef __bf16 bf16x8 __attribute__((ext_vector_type(8)));
typedef float f32x4 __attribute__((ext_vector_type(4)));

#define NTOK 197
#define BATCH 128
#define MROWS (BATCH * NTOK)            // 25216, divisible by 128
#define MTILES_FULL (MROWS / 128)       // 197
#define NB_FULL (6 * MTILES_FULL)       // 1182 blocks per GEMM
#define W_ELEMS ((size_t)768 * 768)
#define BUF_ELEMS_FULL ((size_t)MROWS * 768)
#define PATCH_NBLK (BATCH * 49 * 12 / 4)   // 18816 (%8 == 0)

// fallback chunked config (small-ws safety net)
#define CHUNK_B 8
#define NCHUNK 16
#define MC_CHUNK (CHUNK_B * NTOK)       // 1576
#define MTILES_CHUNK 13
#define BUF_ELEMS_CHUNK ((size_t)MC_CHUNK * 768)

__device__ __forceinline__ unsigned short f2b(float f) {
  unsigned int x = __float_as_uint(f);
  x += 0x7fff + ((x >> 16) & 1);          // RNE
  return (unsigned short)(x >> 16);
}

__device__ __forceinline__ uint4 cvt8pack(float4 f0, float4 f1) {
  unsigned short t8[8] = { f2b(f0.x), f2b(f0.y), f2b(f0.z), f2b(f0.w),
                           f2b(f1.x), f2b(f1.y), f2b(f1.z), f2b(f1.w) };
  return *(const uint4*)t8;
}

#define GLOAD_LDS16(gp, lp)                                                   \
  __builtin_amdgcn_global_load_lds(                                           \
      (const __attribute__((address_space(1))) void*)(gp),                    \
      (__attribute__((address_space(3))) void*)(lp), 16, 0, 0)

// bijective XCD-chunk swizzle (m204)
__device__ __forceinline__ int xcd_swizzle(int bid, int nb) {
  const int q = nb >> 3, r = nb & 7;
  const int xcd = bid & 7, i = bid >> 3;
  return (xcd < r ? xcd * (q + 1) : r * (q + 1) + (xcd - r) * q) + i;
}

// -------- weight transpose+convert: Wt[n*768+k] = bf16(W[k*768+n]) --------
__global__ void transpose768x4(const float* __restrict__ s0, const float* __restrict__ s1,
                               const float* __restrict__ s2, const float* __restrict__ s3,
                               unsigned short* __restrict__ d0, unsigned short* __restrict__ d1,
                               unsigned short* __restrict__ d2, unsigned short* __restrict__ d3) {
  const float* src;
  unsigned short* dst;
  switch (blockIdx.y) {
    case 0: src = s0; dst = d0; break;
    case 1: src = s1; dst = d1; break;
    case 2: src = s2; dst = d2; break;
    default: src = s3; dst = d3; break;
  }
  int idx = blockIdx.x * 256 + threadIdx.x;   // 589824 total
  int n = idx / 768, k = idx % 768;
  dst[idx] = f2b(src[k * 768 + n]);
}

// -------- fp32 -> bf16 bulk convert, 8 elems/thread --------
__global__ void cvt8(const float* __restrict__ src, unsigned short* __restrict__ dst,
                     const int n8) {
  int i = blockIdx.x * 256 + threadIdx.x;
  if (i >= n8) return;
  const float4* p = (const float4*)(src + (size_t)i * 8);
  *(uint4*)(dst + (size_t)i * 8) = cvt8pack(p[0], p[1]);
}

// -------- MFMA tile helpers (128x128 tile, 4 waves 2x2, 4x4 frags) --------
__device__ __forceinline__ void mfma_tile(const unsigned short* sA, const unsigned short* sB,
                                          f32x4 (&acc)[4][4],
                                          const int wr, const int wc,
                                          const int lane16, const int quad) {
  bf16x8 af[4], bf_[4];
  #pragma unroll
  for (int i = 0; i < 4; ++i)
    af[i] = *(const bf16x8*)&sA[(wr * 64 + i * 16 + lane16) * 32 + quad * 8];
  #pragma unroll
  for (int j = 0; j < 4; ++j)
    bf_[j] = *(const bf16x8*)&sB[(wc * 64 + j * 16 + lane16) * 32 + quad * 8];
  #pragma unroll
  for (int i = 0; i < 4; ++i)
    #pragma unroll
    for (int j = 0; j < 4; ++j)
      acc[i][j] = __builtin_amdgcn_mfma_f32_16x16x32_bf16(af[i], bf_[j], acc[i][j], 0, 0, 0);
}

__device__ __forceinline__ void mfma_tile_kv(const unsigned short* sA,
                                             const unsigned short* sBk,
                                             const unsigned short* sBv,
                                             f32x4 (&aK)[4][4], f32x4 (&aV)[4][4],
                                             const int wr, const int wc,
                                             const int lane16, const int quad) {
  bf16x8 af[4], b1[4], b2[4];
  #pragma unroll
  for (int i = 0; i < 4; ++i)
    af[i] = *(const bf16x8*)&sA[(wr * 64 + i * 16 + lane16) * 32 + quad * 8];
  #pragma unroll
  for (int j = 0; j < 4; ++j) {
    b1[j] = *(const bf16x8*)&sBk[(wc * 64 + j * 16 + lane16) * 32 + quad * 8];
    b2[j] = *(const bf16x8*)&sBv[(wc * 64 + j * 16 + lane16) * 32 + quad * 8];
  }
  #pragma unroll
  for (int i = 0; i < 4; ++i)
    #pragma unroll
    for (int j = 0; j < 4; ++j) {
      aK[i][j] = __builtin_amdgcn_mfma_f32_16x16x32_bf16(af[i], b1[j], aK[i][j], 0, 0, 0);
      aV[i][j] = __builtin_amdgcn_mfma_f32_16x16x32_bf16(af[i], b2[j], aV[i][j], 0, 0, 0);
    }
}

__device__ __forceinline__ void epilogue128(f32x4 (&acc)[4][4], const float* __restrict__ bias,
                                            float* __restrict__ C, const int row0, const int n0,
                                            const int wr, const int wc,
                                            const int lane16, const int quad) {
  #pragma unroll
  for (int j = 0; j < 4; ++j) {
    const int col = n0 + wc * 64 + j * 16 + lane16;
    const float bv = bias[col];
    #pragma unroll
    for (int i = 0; i < 4; ++i) {
      const int r0 = row0 + wr * 64 + i * 16 + quad * 4;
      #pragma unroll
      for (int r = 0; r < 4; ++r)
        C[(size_t)(r0 + r) * 768 + col] = acc[i][j][r] + bv;
    }
  }
}

// -------- KV-fused GEMM: K,V = Xb @ {Wk,Wv}^T + b. 2-phase dbuf staging. ----
__global__ __launch_bounds__(256, 2) void kv_gemm(
    const unsigned short* __restrict__ Xb,
    const unsigned short* __restrict__ WkT, const unsigned short* __restrict__ WvT,
    const float* __restrict__ bk, const float* __restrict__ bv,
    float* __restrict__ K, float* __restrict__ V) {
  __shared__ unsigned short lds[2][3][4096];   // [buf][A,Bk,Bv][128*32]
  const int swz = xcd_swizzle(blockIdx.x, NB_FULL);
  const int by = swz / 6, bx = swz % 6;
  const int row0 = by * 128, n0 = bx * 128;
  const int tid = threadIdx.x;
  const int l = tid & 63, w = tid >> 6;
  const int wr = w >> 1, wc = w & 1;
  const int lane16 = l & 15, quad = l >> 4;
  const int rr = tid >> 2, c8 = (tid & 3) * 8;
  const int wbase = (tid & 192) * 8;           // wave-uniform LDS chunk base

  const unsigned short* a0 = Xb + (size_t)(row0 + rr) * 768 + c8;
  const unsigned short* a1 = a0 + (size_t)64 * 768;
  const unsigned short* k0p = WkT + (size_t)(n0 + rr) * 768 + c8;
  const unsigned short* k1p = k0p + (size_t)64 * 768;
  const unsigned short* v0p = WvT + (size_t)(n0 + rr) * 768 + c8;
  const unsigned short* v1p = v0p + (size_t)64 * 768;

  f32x4 aK[4][4] = {}, aV[4][4] = {};

#define STAGE_KV(B, kt) do { const int ko = (kt) * 32;            \
    GLOAD_LDS16(a0 + ko, &lds[B][0][wbase]);                      \
    GLOAD_LDS16(a1 + ko, &lds[B][0][wbase + 2048]);               \
    GLOAD_LDS16(k0p + ko, &lds[B][1][wbase]);                     \
    GLOAD_LDS16(k1p + ko, &lds[B][1][wbase + 2048]);              \
    GLOAD_LDS16(v0p + ko, &lds[B][2][wbase]);                     \
    GLOAD_LDS16(v1p + ko, &lds[B][2][wbase + 2048]); } while (0)

  STAGE_KV(0, 0);
  __syncthreads();
  for (int kt = 0; kt < 23; ++kt) {
    const int cur = kt & 1;
    STAGE_KV(cur ^ 1, kt + 1);
    mfma_tile_kv(&lds[cur][0][0], &lds[cur][1][0], &lds[cur][2][0],
                 aK, aV, wr, wc, lane16, quad);
    __syncthreads();
  }
  mfma_tile_kv(&lds[1][0][0], &lds[1][1][0], &lds[1][2][0],
               aK, aV, wr, wc, lane16, quad);
#undef STAGE_KV

  epilogue128(aK, bk, K, row0, n0, wr, wc, lane16, quad);
  epilogue128(aV, bv, V, row0, n0, wr, wc, lane16, quad);
}

// -------- O GEMM: out = ATTb @ Wo^T + bo. bf16 A, 2-phase dbuf. ------------
__global__ __launch_bounds__(256, 2) void o_gemm(
    const unsigned short* __restrict__ Ab, const unsigned short* __restrict__ WoT,
    const float* __restrict__ bo, float* __restrict__ C) {
  __shared__ unsigned short lds[2][2][4096];   // [buf][A,B][128*32]
  const int swz = xcd_swizzle(blockIdx.x, NB_FULL);
  const int by = swz / 6, bx = swz % 6;
  const int row0 = by * 128, n0 = bx * 128;
  const int tid = threadIdx.x;
  const int l = tid & 63, w = tid >> 6;
  const int wr = w >> 1, wc = w & 1;
  const int lane16 = l & 15, quad = l >> 4;
  const int rr = tid >> 2, c8 = (tid & 3) * 8;
  const int wbase = (tid & 192) * 8;

  const unsigned short* a0 = Ab + (size_t)(row0 + rr) * 768 + c8;
  const unsigned short* a1 = a0 + (size_t)64 * 768;
  const unsigned short* b0 = WoT + (size_t)(n0 + rr) * 768 + c8;
  const unsigned short* b1 = b0 + (size_t)64 * 768;

  f32x4 acc[4][4] = {};

#define STAGE_O(B, kt) do { const int ko = (kt) * 32;             \
    GLOAD_LDS16(a0 + ko, &lds[B][0][wbase]);                      \
    GLOAD_LDS16(a1 + ko, &lds[B][0][wbase + 2048]);               \
    GLOAD_LDS16(b0 + ko, &lds[B][1][wbase]);                      \
    GLOAD_LDS16(b1 + ko, &lds[B][1][wbase + 2048]); } while (0)

  STAGE_O(0, 0);
  __syncthreads();
  for (int kt = 0; kt < 23; ++kt) {
    const int cur = kt & 1;
    STAGE_O(cur ^ 1, kt + 1);
    mfma_tile(&lds[cur][0][0], &lds[cur][1][0], acc, wr, wc, lane16, quad);
    __syncthreads();
  }
  mfma_tile(&lds[1][0][0], &lds[1][1][0], acc, wr, wc, lane16, quad);
#undef STAGE_O

  epilogue128(acc, bo, C, row0, n0, wr, wc, lane16, quad);
}

// -------- Q GEMM: fp32 A reg-staged (load-early/convert-late), B dbuf. -----
__global__ __launch_bounds__(256, 2) void q_gemm(
    const float* __restrict__ Y, const unsigned short* __restrict__ WqT,
    const float* __restrict__ bq, float* __restrict__ Q) {
  __shared__ unsigned short As[2][4096];
  __shared__ unsigned short Bs[2][4096];
  const int swz = xcd_swizzle(blockIdx.x, NB_FULL);
  const int by = swz / 6, bx = swz % 6;
  const int row0 = by * 128, n0 = bx * 128;
  const int tid = threadIdx.x;
  const int l = tid & 63, w = tid >> 6;
  const int wr = w >> 1, wc = w & 1;
  const int lane16 = l & 15, quad = l >> 4;
  const int rr = tid >> 2, c8 = (tid & 3) * 8;
  const int wbase = (tid & 192) * 8;

  const float* y0 = Y + (size_t)(row0 + rr) * 768 + c8;
  const float* y1 = y0 + (size_t)64 * 768;
  const unsigned short* b0 = WqT + (size_t)(n0 + rr) * 768 + c8;
  const unsigned short* b1 = b0 + (size_t)64 * 768;

  f32x4 acc[4][4] = {};

  // prologue: tile 0
  float4 f0 = *(const float4*)y0, f1 = *(const float4*)(y0 + 4);
  float4 g0 = *(const float4*)y1, g1 = *(const float4*)(y1 + 4);
  GLOAD_LDS16(b0, &Bs[0][wbase]);
  GLOAD_LDS16(b1, &Bs[0][wbase + 2048]);
  *(uint4*)&As[0][rr * 32 + c8] = cvt8pack(f0, f1);
  *(uint4*)&As[0][(64 + rr) * 32 + c8] = cvt8pack(g0, g1);
  __syncthreads();

  for (int kt = 0; kt < 23; ++kt) {
    const int cur = kt & 1, nxt = cur ^ 1;
    const int ko = (kt + 1) * 32;
    f0 = *(const float4*)(y0 + ko); f1 = *(const float4*)(y0 + ko + 4);
    g0 = *(const float4*)(y1 + ko); g1 = *(const float4*)(y1 + ko + 4);
    GLOAD_LDS16(b0 + ko, &Bs[nxt][wbase]);
    GLOAD_LDS16(b1 + ko, &Bs[nxt][wbase + 2048]);
    mfma_tile(&As[cur][0], &Bs[cur][0], acc, wr, wc, lane16, quad);
    *(uint4*)&As[nxt][rr * 32 + c8] = cvt8pack(f0, f1);
    *(uint4*)&As[nxt][(64 + rr) * 32 + c8] = cvt8pack(g0, g1);
    __syncthreads();
  }
  mfma_tile(&As[1][0], &Bs[1][0], acc, wr, wc, lane16, quad);

  epilogue128(acc, bq, Q, row0, n0, wr, wc, lane16, quad);
}

// ==================== fallback (chunked) GEMM bodies ====================
__device__ __forceinline__ void gemm_body_f32A(
    const float* __restrict__ A, const unsigned short* __restrict__ Wt,
    const float* __restrict__ bias, float* __restrict__ C,
    const int row0, const int n0, const int Mrows, unsigned short* sAB) {
  const int tid = threadIdx.x;
  const int l = tid & 63, w = tid >> 6;
  const int wr = w >> 1, wc = w & 1;
  const int lane16 = l & 15, quad = l >> 4;

  f32x4 acc[4][4] = {};

  for (int kt = 0; kt < 24; ++kt) {
    const int k0 = kt * 32;
    #pragma unroll
    for (int i = 0; i < 2; ++i) {
      const int ch = i * 256 + tid;
      const int rr2 = ch >> 2;
      const int c82 = (ch & 3) * 8;
      int ra = row0 + rr2; if (ra > Mrows - 1) ra = Mrows - 1;
      const float* ap = A + (size_t)ra * 768 + k0 + c82;
      float4 q0 = *(const float4*)ap;
      float4 q1 = *(const float4*)(ap + 4);
      *(uint4*)&sAB[rr2 * 32 + c82] = cvt8pack(q0, q1);
      uint4 vb = *(const uint4*)(Wt + (size_t)(n0 + rr2) * 768 + k0 + c82);
      *(uint4*)&sAB[4096 + rr2 * 32 + c82] = vb;
    }
    __syncthreads();
    mfma_tile(sAB, sAB + 4096, acc, wr, wc, lane16, quad);
    __syncthreads();
  }
  #pragma unroll
  for (int j = 0; j < 4; ++j) {
    const int col = n0 + wc * 64 + j * 16 + lane16;
    const float bv = bias[col];
    #pragma unroll
    for (int i = 0; i < 4; ++i) {
      const int r0 = row0 + wr * 64 + i * 16 + quad * 4;
      #pragma unroll
      for (int r = 0; r < 4; ++r)
        if (r0 + r < Mrows)
          C[(size_t)(r0 + r) * 768 + col] = acc[i][j][r] + bv;
    }
  }
}

__global__ __launch_bounds__(256, 2) void qkv_gemm(
    const float* __restrict__ X, const float* __restrict__ Y,
    const unsigned short* __restrict__ WkT, const unsigned short* __restrict__ WvT,
    const unsigned short* __restrict__ WqT,
    const float* __restrict__ bk, const float* __restrict__ bv, const float* __restrict__ bq,
    float* __restrict__ K, float* __restrict__ V, float* __restrict__ Q,
    const int Mrows) {
  __shared__ unsigned short sAB[8192];
  const int mat = blockIdx.x / 6;
  const int n0 = (blockIdx.x % 6) * 128;
  const float* A = (mat == 2) ? Y : X;
  const unsigned short* Wt = (mat == 0) ? WkT : (mat == 1) ? WvT : WqT;
  const float* bias = (mat == 0) ? bk : (mat == 1) ? bv : bq;
  float* C = (mat == 0) ? K : (mat == 1) ? V : Q;
  gemm_body_f32A(A, Wt, bias, C, blockIdx.y * 128, n0, Mrows, sAB);
}

__global__ __launch_bounds__(256, 2) void gemm_bt(
    const float* __restrict__ A, const unsigned short* __restrict__ Wt,
    const float* __restrict__ bias, float* __restrict__ C, const int Mrows) {
  __shared__ unsigned short sAB[8192];
  gemm_body_f32A(A, Wt, bias, C, blockIdx.y * 128, blockIdx.x * 128, Mrows, sAB);
}

// ==================== attention ====================
__device__ __forceinline__ float cls_attn_body(const float* __restrict__ Q,
                                               const float* __restrict__ K,
                                               const float* __restrict__ V,
                                               const size_t rowbase,
                                               float* q, float* attn, float* red) {
  const int tid = threadIdx.x, l = tid & 63, w = tid >> 6;
  if (tid < 64) q[tid] = Q[rowbase + tid];
  __syncthreads();

  float d = -3e38f;
  if (tid < NTOK) {
    const float4* Kp = (const float4*)(K + rowbase + (size_t)tid * 768);
    float s = 0.f;
    #pragma unroll
    for (int u = 0; u < 16; ++u) {
      float4 kk = Kp[u];
      s += q[u * 4 + 0] * kk.x + q[u * 4 + 1] * kk.y
         + q[u * 4 + 2] * kk.z + q[u * 4 + 3] * kk.w;
    }
    d = s * 0.125f;
  }
  float m = d;
  #pragma unroll
  for (int off = 32; off; off >>= 1) m = fmaxf(m, __shfl_xor(m, off, 64));
  if (l == 0) red[w] = m;
  __syncthreads();
  const float M = fmaxf(fmaxf(red[0], red[1]), fmaxf(red[2], red[3]));
  float e = (tid < NTOK) ? __expf(d - M) : 0.f;
  float ssum = e;
  #pragma unroll
  for (int off = 32; off; off >>= 1) ssum += __shfl_xor(ssum, off, 64);
  if (l == 0) red[4 + w] = ssum;
  __syncthreads();
  const float S = red[4] + red[5] + red[6] + red[7];
  attn[tid] = e / S;
  __syncthreads();
  float o = 0.f;
  if (tid < 64) {
    for (int j = 0; j < NTOK; ++j)
      o += attn[j] * V[rowbase + (size_t)j * 768 + tid];
  }
  return o;
}

__global__ void cls_attn_b(const float* __restrict__ Q, const float* __restrict__ K,
                           const float* __restrict__ V, unsigned short* __restrict__ ATT) {
  __shared__ float q[64];
  __shared__ float attn[256];
  __shared__ float red[8];
  const int b = blockIdx.x / 12, h = blockIdx.x % 12;
  const size_t rowbase = ((size_t)b * NTOK) * 768 + h * 64;
  float o = cls_attn_body(Q, K, V, rowbase, q, attn, red);
  if (threadIdx.x < 64) ATT[rowbase + threadIdx.x] = f2b(o);
}

__global__ void cls_attn(const float* __restrict__ Q, const float* __restrict__ K,
                         const float* __restrict__ V, float* __restrict__ ATT) {
  __shared__ float q[64];
  __shared__ float attn[256];
  __shared__ float red[8];
  const int b = blockIdx.x / 12, h = blockIdx.x % 12;
  const size_t rowbase = ((size_t)b * NTOK) * 768 + h * 64;
  float o = cls_attn_body(Q, K, V, rowbase, q, attn, red);
  if (threadIdx.x < 64) ATT[rowbase + threadIdx.x] = o;
}

// -------- patch tokens, fast path: 1 wave = 4 patches, 16 lanes/patch ------
// lane = pg*16 + t16 ; t16 owns d = t16*4 .. t16*4+3 (float4)
__global__ __launch_bounds__(256) void patch_attn4_b(
    const float* __restrict__ Q, const float* __restrict__ K,
    const float* __restrict__ V, unsigned short* __restrict__ ATT) {
  const int swb = xcd_swizzle(blockIdx.x, PATCH_NBLK);
  const int wu = swb * 4 + (threadIdx.x >> 6);   // (b, pq, h), h fastest
  const int l = threadIdx.x & 63;
  const int t16 = l & 15, pg = l >> 4;
  const int h = wu % 12;
  const int t2 = wu / 12;
  const int pq = t2 % 49;
  const int b = t2 / 49;
  const int p = pq * 4 + pg;                     // 0..195 (49*4 == 196 exact)
  const int r = p / 14, c = p % 14;
  const size_t ib = ((size_t)b * NTOK) * 768 + h * 64 + t16 * 4;

  const float4 q = *(const float4*)(Q + ib + (size_t)(p + 1) * 768);

  float s[9];
  int tok[9];
  #pragma unroll
  for (int jj = 0; jj < 9; ++jj) {
    const int nr = r + jj / 3 - 1, nc = c + jj % 3 - 1;
    const bool ok = ((unsigned)nr < 14u) && ((unsigned)nc < 14u);
    tok[jj] = ok ? (1 + nr * 14 + nc) : (p + 1);
    const float4 kk = *(const float4*)(K + ib + (size_t)tok[jj] * 768);
    float d = q.x * kk.x + q.y * kk.y + q.z * kk.z + q.w * kk.w;
    d += __shfl_xor(d, 1);
    d += __shfl_xor(d, 2);
    d += __shfl_xor(d, 4);
    d += __shfl_xor(d, 8);                       // 16-lane group sum
    s[jj] = ok ? d * 0.125f : -3e38f;
  }
  float m = s[0];
  #pragma unroll
  for (int jj = 1; jj < 9; ++jj) m = fmaxf(m, s[jj]);
  float sum = 0.f;
  #pragma unroll
  for (int jj = 0; jj < 9; ++jj) { s[jj] = __expf(s[jj] - m); sum += s[jj]; }
  const float inv = 1.f / sum;

  float4 o = {0.f, 0.f, 0.f, 0.f};
  #pragma unroll
  for (int jj = 0; jj < 9; ++jj) {
    const float4 vv = *(const float4*)(V + ib + (size_t)tok[jj] * 768);
    o.x += s[jj] * vv.x; o.y += s[jj] * vv.y;
    o.z += s[jj] * vv.z; o.w += s[jj] * vv.w;
  }
  o.x *= inv; o.y *= inv; o.z *= inv; o.w *= inv;
  unsigned short t4[4] = { f2b(o.x), f2b(o.y), f2b(o.z), f2b(o.w) };
  *(ushort2*)&ATT[ib + (size_t)(p + 1) * 768] = *(const ushort2*)&t4[0];
  *(ushort2*)&ATT[ib + (size_t)(p + 1) * 768 + 2] = *(const ushort2*)&t4[2];
}

// fallback scalar patch kernel (fp32 out)
__device__ __forceinline__ float patch_attn_body(const float* __restrict__ Q,
                                                 const float* __restrict__ K,
                                                 const float* __restrict__ V,
                                                 const size_t base, const int p,
                                                 const int r, const int c) {
  const float qd = Q[base + (size_t)(p + 1) * 768];

  float s[9];
  int tok[9];
  #pragma unroll
  for (int jj = 0; jj < 9; ++jj) {
    const int nr = r + jj / 3 - 1, nc = c + jj % 3 - 1;
    const bool ok = ((unsigned)nr < 14u) && ((unsigned)nc < 14u);
    tok[jj] = ok ? (1 + nr * 14 + nc) : (p + 1);
    float d = qd * K[base + (size_t)tok[jj] * 768];
    #pragma unroll
    for (int off = 32; off; off >>= 1) d += __shfl_xor(d, off, 64);
    s[jj] = ok ? d * 0.125f : -3e38f;
  }
  float m = s[0];
  #pragma unroll
  for (int jj = 1; jj < 9; ++jj) m = fmaxf(m, s[jj]);
  float sum = 0.f;
  #pragma unroll
  for (int jj = 0; jj < 9; ++jj) { s[jj] = __expf(s[jj] - m); sum += s[jj]; }
  const float inv = 1.f / sum;
  float o = 0.f;
  #pragma unroll
  for (int jj = 0; jj < 9; ++jj) o += s[jj] * V[base + (size_t)tok[jj] * 768];
  return o * inv;
}

__global__ void patch_attn(const float* __restrict__ Q, const float* __restrict__ K,
                           const float* __restrict__ V, float* __restrict__ ATT) {
  const int wgid = blockIdx.x * 4 + (threadIdx.x >> 6);
  const int l = threadIdx.x & 63;
  const int h = wgid % 12;
  const int t2 = wgid / 12;
  const int p = t2 % 196;
  const int b = t2 / 196;
  const int r = p / 14, c = p % 14;
  const size_t base = ((size_t)b * NTOK) * 768 + h * 64 + l;
  float o = patch_attn_body(Q, K, V, base, p, r, c);
  ATT[base + (size_t)(p + 1) * 768] = o;
}

extern "C" void kernel_launch(void* const* d_in, const int* in_sizes, int n_in,
                              void* d_out, int out_size, void* d_ws, size_t ws_size,
                              hipStream_t stream) {
  const float* x  = (const float*)d_in[0];
  const float* y  = (const float*)d_in[1];
  const float* Wq = (const float*)d_in[2];
  const float* bq = (const float*)d_in[3];
  const float* Wk = (const float*)d_in[4];
  const float* bk = (const float*)d_in[5];
  const float* Wv = (const float*)d_in[6];
  const float* bv = (const float*)d_in[7];
  const float* Wo = (const float*)d_in[8];
  const float* bo = (const float*)d_in[9];
  float* out = (float*)d_out;

  unsigned short* WqT = (unsigned short*)d_ws;
  unsigned short* WkT = WqT + W_ELEMS;
  unsigned short* WvT = WkT + W_ELEMS;
  unsigned short* WoT = WvT + W_ELEMS;

  transpose768x4<<<dim3(2304, 4), 256, 0, stream>>>(Wq, Wk, Wv, Wo, WqT, WkT, WvT, WoT);

  const size_t need_full = 4 * W_ELEMS * sizeof(unsigned short)
                         + BUF_ELEMS_FULL * sizeof(unsigned short)   // Xb / ATTb
                         + 3 * BUF_ELEMS_FULL * sizeof(float);       // K,V,Q
  if (ws_size >= need_full) {
    // ---- full-batch path: 7 launches ----
    unsigned short* Xb = WoT + W_ELEMS;          // aliased by ATTb after qkv
    unsigned short* ATTb = Xb;
    float* Kc = (float*)(Xb + BUF_ELEMS_FULL);
    float* Vc = Kc + BUF_ELEMS_FULL;
    float* Qc = Vc + BUF_ELEMS_FULL;

    const int n8 = (int)(BUF_ELEMS_FULL / 8);
    cvt8<<<n8 / 256, 256, 0, stream>>>(x, Xb, n8);

    kv_gemm<<<NB_FULL, 256, 0, stream>>>(Xb, WkT, WvT, bk, bv, Kc, Vc);
    q_gemm<<<NB_FULL, 256, 0, stream>>>(y, WqT, bq, Qc);
    cls_attn_b<<<BATCH * 12, 256, 0, stream>>>(Qc, Kc, Vc, ATTb);
    patch_attn4_b<<<PATCH_NBLK, 256, 0, stream>>>(Qc, Kc, Vc, ATTb);
    o_gemm<<<NB_FULL, 256, 0, stream>>>(ATTb, WoT, bo, out);
  } else {
    // ---- fallback: old 16-chunk flow (ws ~19 MB) ----
    float* Kc = (float*)(WoT + W_ELEMS);
    float* Vc = Kc + BUF_ELEMS_CHUNK;
    float* Qc = Vc + BUF_ELEMS_CHUNK;

    for (int c = 0; c < NCHUNK; ++c) {
      const float* xc = x + (size_t)c * BUF_ELEMS_CHUNK;
      const float* yc = y + (size_t)c * BUF_ELEMS_CHUNK;
      qkv_gemm<<<dim3(18, MTILES_CHUNK), 256, 0, stream>>>(
          xc, yc, WkT, WvT, WqT, bk, bv, bq, Kc, Vc, Qc, MC_CHUNK);
      cls_attn<<<CHUNK_B * 12, 256, 0, stream>>>(Qc, Kc, Vc, Qc);
      patch_attn<<<(CHUNK_B * 196 * 12) / 4, 256, 0, stream>>>(Qc, Kc, Vc, Qc);
      gemm_bt<<<dim3(6, MTILES_CHUNK), 256, 0, stream>>>(Qc, WoT, bo,
                                                         out + (size_t)c * BUF_ELEMS_CHUNK, MC_CHUNK);
    }
  }
}

// Round 5
// 511.867 us; speedup vs baseline: 5.4207x; 1.0865x over previous
//
#include <hip/hip_runtime.h>

// CrossAttention: x_qkv->K,V ; y_q->Q ; CLS full attn + patch 3x3 local attn ; @Wo+bo
// I/O fp32. Internals: bf16 MFMA GEMMs.
//
// THIS VERSION (vs round-4):
//  - Unified gemm_bf16 for K,V,Q,O projections: bf16 A via global_load_lds,
//    two-barrier COUNTED-vmcnt pipeline (T3/T4: STAGE(next); vmcnt(4);
//    barrier; MFMA(cur); barrier) so prefetch loads stay in flight across
//    barriers (old __syncthreads drained them -> 700cyc/K-step stall).
//  - __launch_bounds__(256,4): 4 blocks/CU (was 2). KV un-fused so the
//    accumulator fits 128 regs/wave (fused needed 188 -> capped at 2).
//  - Y converted to bf16 once into the region Xb vacates after V-GEMM
//    (Xb -> Yb -> ATTb all alias one 38.7MB region; strictly sequential).
//  - cls_attn: V-accumulation now uses all 256 threads (4 j-groups + LDS
//    reduce) instead of 64 threads x 197 iters.
// patch_attn4_b / transpose / cvt8 unchanged from round-4.

typedef __bf16 bf16x8 __attribute__((ext_vector_type(8)));
typedef float f32x4 __attribute__((ext_vector_type(4)));

#define NTOK 197
#define BATCH 128
#define MROWS (BATCH * NTOK)            // 25216, divisible by 128
#define MTILES_FULL (MROWS / 128)       // 197
#define NB_FULL (6 * MTILES_FULL)       // 1182 blocks per GEMM
#define W_ELEMS ((size_t)768 * 768)
#define BUF_ELEMS_FULL ((size_t)MROWS * 768)
#define PATCH_NBLK (BATCH * 49 * 12 / 4)   // 18816

// fallback chunked config (small-ws safety net)
#define CHUNK_B 8
#define NCHUNK 16
#define MC_CHUNK (CHUNK_B * NTOK)       // 1576
#define MTILES_CHUNK 13
#define BUF_ELEMS_CHUNK ((size_t)MC_CHUNK * 768)

__device__ __forceinline__ unsigned short f2b(float f) {
  unsigned int x = __float_as_uint(f);
  x += 0x7fff + ((x >> 16) & 1);          // RNE
  return (unsigned short)(x >> 16);
}

__device__ __forceinline__ uint4 cvt8pack(float4 f0, float4 f1) {
  unsigned short t8[8] = { f2b(f0.x), f2b(f0.y), f2b(f0.z), f2b(f0.w),
                           f2b(f1.x), f2b(f1.y), f2b(f1.z), f2b(f1.w) };
  return *(const uint4*)t8;
}

#define GLOAD_LDS16(gp, lp)                                                   \
  __builtin_amdgcn_global_load_lds(                                           \
      (const __attribute__((address_space(1))) void*)(gp),                    \
      (__attribute__((address_space(3))) void*)(lp), 16, 0, 0)

// bijective XCD-chunk swizzle (m204)
__device__ __forceinline__ int xcd_swizzle(int bid, int nb) {
  const int q = nb >> 3, r = nb & 7;
  const int xcd = bid & 7, i = bid >> 3;
  return (xcd < r ? xcd * (q + 1) : r * (q + 1) + (xcd - r) * q) + i;
}

// -------- weight transpose+convert: Wt[n*768+k] = bf16(W[k*768+n]) --------
__global__ void transpose768x4(const float* __restrict__ s0, const float* __restrict__ s1,
                               const float* __restrict__ s2, const float* __restrict__ s3,
                               unsigned short* __restrict__ d0, unsigned short* __restrict__ d1,
                               unsigned short* __restrict__ d2, unsigned short* __restrict__ d3) {
  const float* src;
  unsigned short* dst;
  switch (blockIdx.y) {
    case 0: src = s0; dst = d0; break;
    case 1: src = s1; dst = d1; break;
    case 2: src = s2; dst = d2; break;
    default: src = s3; dst = d3; break;
  }
  int idx = blockIdx.x * 256 + threadIdx.x;   // 589824 total
  int n = idx / 768, k = idx % 768;
  dst[idx] = f2b(src[k * 768 + n]);
}

// -------- fp32 -> bf16 bulk convert, 8 elems/thread --------
__global__ void cvt8(const float* __restrict__ src, unsigned short* __restrict__ dst,
                     const int n8) {
  int i = blockIdx.x * 256 + threadIdx.x;
  if (i >= n8) return;
  const float4* p = (const float4*)(src + (size_t)i * 8);
  *(uint4*)(dst + (size_t)i * 8) = cvt8pack(p[0], p[1]);
}

// -------- MFMA tile helpers (128x128 tile, 4 waves 2x2, 4x4 frags) --------
__device__ __forceinline__ void mfma_tile(const unsigned short* sA, const unsigned short* sB,
                                          f32x4 (&acc)[4][4],
                                          const int wr, const int wc,
                                          const int lane16, const int quad) {
  bf16x8 af[4], bf_[4];
  #pragma unroll
  for (int i = 0; i < 4; ++i)
    af[i] = *(const bf16x8*)&sA[(wr * 64 + i * 16 + lane16) * 32 + quad * 8];
  #pragma unroll
  for (int j = 0; j < 4; ++j)
    bf_[j] = *(const bf16x8*)&sB[(wc * 64 + j * 16 + lane16) * 32 + quad * 8];
  #pragma unroll
  for (int i = 0; i < 4; ++i)
    #pragma unroll
    for (int j = 0; j < 4; ++j)
      acc[i][j] = __builtin_amdgcn_mfma_f32_16x16x32_bf16(af[i], bf_[j], acc[i][j], 0, 0, 0);
}

__device__ __forceinline__ void epilogue128(f32x4 (&acc)[4][4], const float* __restrict__ bias,
                                            float* __restrict__ C, const int row0, const int n0,
                                            const int wr, const int wc,
                                            const int lane16, const int quad) {
  #pragma unroll
  for (int j = 0; j < 4; ++j) {
    const int col = n0 + wc * 64 + j * 16 + lane16;
    const float bv = bias[col];
    #pragma unroll
    for (int i = 0; i < 4; ++i) {
      const int r0 = row0 + wr * 64 + i * 16 + quad * 4;
      #pragma unroll
      for (int r = 0; r < 4; ++r)
        C[(size_t)(r0 + r) * 768 + col] = acc[i][j][r] + bv;
    }
  }
}

// -------- unified bf16-A GEMM: C[MROWS,768] = A @ Bt^T + bias --------------
// Counted-vmcnt two-barrier pipeline; 4 blocks/CU.
__global__ __launch_bounds__(256, 4) void gemm_bf16(
    const unsigned short* __restrict__ A, const unsigned short* __restrict__ Bt,
    const float* __restrict__ bias, float* __restrict__ C) {
  __shared__ unsigned short lds[2][2][4096];   // [buf][A,B][128*32]
  const int swz = xcd_swizzle(blockIdx.x, NB_FULL);
  const int by = swz / 6, bx = swz % 6;
  const int row0 = by * 128, n0 = bx * 128;
  const int tid = threadIdx.x;
  const int l = tid & 63, w = tid >> 6;
  const int wr = w >> 1, wc = w & 1;
  const int lane16 = l & 15, quad = l >> 4;
  const int rr = tid >> 2, c8 = (tid & 3) * 8;
  const int wbase = (tid & 192) * 8;           // wave-uniform LDS chunk base

  const unsigned short* a0 = A + (size_t)(row0 + rr) * 768 + c8;
  const unsigned short* a1 = a0 + (size_t)64 * 768;
  const unsigned short* b0 = Bt + (size_t)(n0 + rr) * 768 + c8;
  const unsigned short* b1 = b0 + (size_t)64 * 768;

  f32x4 acc[4][4] = {};

#define STAGE_G(B, kt) do { const int ko = (kt) * 32;             \
    GLOAD_LDS16(a0 + ko, &lds[B][0][wbase]);                      \
    GLOAD_LDS16(a1 + ko, &lds[B][0][wbase + 2048]);               \
    GLOAD_LDS16(b0 + ko, &lds[B][1][wbase]);                      \
    GLOAD_LDS16(b1 + ko, &lds[B][1][wbase + 2048]); } while (0)

  STAGE_G(0, 0);
  int cur = 0;
  for (int kt = 0; kt < 23; ++kt) {
    STAGE_G(cur ^ 1, kt + 1);                          // 4 loads in flight
    asm volatile("s_waitcnt vmcnt(4)" ::: "memory");   // cur's loads landed
    __builtin_amdgcn_s_barrier();                      // all waves agree
    __builtin_amdgcn_sched_barrier(0);
    mfma_tile(&lds[cur][0][0], &lds[cur][1][0], acc, wr, wc, lane16, quad);
    __builtin_amdgcn_s_barrier();                      // reads done before overwrite
    cur ^= 1;
  }
  asm volatile("s_waitcnt vmcnt(0)" ::: "memory");
  __builtin_amdgcn_s_barrier();
  __builtin_amdgcn_sched_barrier(0);
  mfma_tile(&lds[cur][0][0], &lds[cur][1][0], acc, wr, wc, lane16, quad);
#undef STAGE_G

  epilogue128(acc, bias, C, row0, n0, wr, wc, lane16, quad);
}

// ==================== fallback (chunked) GEMM bodies ====================
__device__ __forceinline__ void gemm_body_f32A(
    const float* __restrict__ A, const unsigned short* __restrict__ Wt,
    const float* __restrict__ bias, float* __restrict__ C,
    const int row0, const int n0, const int Mrows, unsigned short* sAB) {
  const int tid = threadIdx.x;
  const int l = tid & 63, w = tid >> 6;
  const int wr = w >> 1, wc = w & 1;
  const int lane16 = l & 15, quad = l >> 4;

  f32x4 acc[4][4] = {};

  for (int kt = 0; kt < 24; ++kt) {
    const int k0 = kt * 32;
    #pragma unroll
    for (int i = 0; i < 2; ++i) {
      const int ch = i * 256 + tid;
      const int rr2 = ch >> 2;
      const int c82 = (ch & 3) * 8;
      int ra = row0 + rr2; if (ra > Mrows - 1) ra = Mrows - 1;
      const float* ap = A + (size_t)ra * 768 + k0 + c82;
      float4 q0 = *(const float4*)ap;
      float4 q1 = *(const float4*)(ap + 4);
      *(uint4*)&sAB[rr2 * 32 + c82] = cvt8pack(q0, q1);
      uint4 vb = *(const uint4*)(Wt + (size_t)(n0 + rr2) * 768 + k0 + c82);
      *(uint4*)&sAB[4096 + rr2 * 32 + c82] = vb;
    }
    __syncthreads();
    mfma_tile(sAB, sAB + 4096, acc, wr, wc, lane16, quad);
    __syncthreads();
  }
  #pragma unroll
  for (int j = 0; j < 4; ++j) {
    const int col = n0 + wc * 64 + j * 16 + lane16;
    const float bv = bias[col];
    #pragma unroll
    for (int i = 0; i < 4; ++i) {
      const int r0 = row0 + wr * 64 + i * 16 + quad * 4;
      #pragma unroll
      for (int r = 0; r < 4; ++r)
        if (r0 + r < Mrows)
          C[(size_t)(r0 + r) * 768 + col] = acc[i][j][r] + bv;
    }
  }
}

__global__ __launch_bounds__(256, 2) void qkv_gemm(
    const float* __restrict__ X, const float* __restrict__ Y,
    const unsigned short* __restrict__ WkT, const unsigned short* __restrict__ WvT,
    const unsigned short* __restrict__ WqT,
    const float* __restrict__ bk, const float* __restrict__ bv, const float* __restrict__ bq,
    float* __restrict__ K, float* __restrict__ V, float* __restrict__ Q,
    const int Mrows) {
  __shared__ unsigned short sAB[8192];
  const int mat = blockIdx.x / 6;
  const int n0 = (blockIdx.x % 6) * 128;
  const float* A = (mat == 2) ? Y : X;
  const unsigned short* Wt = (mat == 0) ? WkT : (mat == 1) ? WvT : WqT;
  const float* bias = (mat == 0) ? bk : (mat == 1) ? bv : bq;
  float* C = (mat == 0) ? K : (mat == 1) ? V : Q;
  gemm_body_f32A(A, Wt, bias, C, blockIdx.y * 128, n0, Mrows, sAB);
}

__global__ __launch_bounds__(256, 2) void gemm_bt(
    const float* __restrict__ A, const unsigned short* __restrict__ Wt,
    const float* __restrict__ bias, float* __restrict__ C, const int Mrows) {
  __shared__ unsigned short sAB[8192];
  gemm_body_f32A(A, Wt, bias, C, blockIdx.y * 128, blockIdx.x * 128, Mrows, sAB);
}

// ==================== attention ====================
// CLS full attention: dots wave-parallel, V-accum uses ALL 256 threads.
__global__ void cls_attn_b(const float* __restrict__ Q, const float* __restrict__ K,
                           const float* __restrict__ V, unsigned short* __restrict__ ATT) {
  __shared__ float q[64];
  __shared__ float attn[256];
  __shared__ float red[8];
  __shared__ float part[4][64];
  const int tid = threadIdx.x, l = tid & 63, w = tid >> 6;
  const int b = blockIdx.x / 12, h = blockIdx.x % 12;
  const size_t rowbase = ((size_t)b * NTOK) * 768 + h * 64;

  if (tid < 64) q[tid] = Q[rowbase + tid];
  __syncthreads();

  float d = -3e38f;
  if (tid < NTOK) {
    const float4* Kp = (const float4*)(K + rowbase + (size_t)tid * 768);
    float s = 0.f;
    #pragma unroll
    for (int u = 0; u < 16; ++u) {
      float4 kk = Kp[u];
      s += q[u * 4 + 0] * kk.x + q[u * 4 + 1] * kk.y
         + q[u * 4 + 2] * kk.z + q[u * 4 + 3] * kk.w;
    }
    d = s * 0.125f;
  }
  float m = d;
  #pragma unroll
  for (int off = 32; off; off >>= 1) m = fmaxf(m, __shfl_xor(m, off, 64));
  if (l == 0) red[w] = m;
  __syncthreads();
  const float M = fmaxf(fmaxf(red[0], red[1]), fmaxf(red[2], red[3]));
  float e = (tid < NTOK) ? __expf(d - M) : 0.f;
  float ssum = e;
  #pragma unroll
  for (int off = 32; off; off >>= 1) ssum += __shfl_xor(ssum, off, 64);
  if (l == 0) red[4 + w] = ssum;
  __syncthreads();
  const float S = red[4] + red[5] + red[6] + red[7];
  attn[tid] = e / S;
  __syncthreads();

  // V accumulation: thread (jg, dd); wave-group jg takes j = jg, jg+4, ...
  const int dd = tid & 63, jg = tid >> 6;
  float o = 0.f;
  for (int j = jg; j < NTOK; j += 4)
    o += attn[j] * V[rowbase + (size_t)j * 768 + dd];
  part[jg][dd] = o;
  __syncthreads();
  if (tid < 64) {
    const float r = part[0][tid] + part[1][tid] + part[2][tid] + part[3][tid];
    ATT[rowbase + tid] = f2b(r);
  }
}

// fallback fp32-out CLS (old structure)
__device__ __forceinline__ float cls_attn_body(const float* __restrict__ Q,
                                               const float* __restrict__ K,
                                               const float* __restrict__ V,
                                               const size_t rowbase,
                                               float* q, float* attn, float* red) {
  const int tid = threadIdx.x, l = tid & 63, w = tid >> 6;
  if (tid < 64) q[tid] = Q[rowbase + tid];
  __syncthreads();

  float d = -3e38f;
  if (tid < NTOK) {
    const float4* Kp = (const float4*)(K + rowbase + (size_t)tid * 768);
    float s = 0.f;
    #pragma unroll
    for (int u = 0; u < 16; ++u) {
      float4 kk = Kp[u];
      s += q[u * 4 + 0] * kk.x + q[u * 4 + 1] * kk.y
         + q[u * 4 + 2] * kk.z + q[u * 4 + 3] * kk.w;
    }
    d = s * 0.125f;
  }
  float m = d;
  #pragma unroll
  for (int off = 32; off; off >>= 1) m = fmaxf(m, __shfl_xor(m, off, 64));
  if (l == 0) red[w] = m;
  __syncthreads();
  const float M = fmaxf(fmaxf(red[0], red[1]), fmaxf(red[2], red[3]));
  float e = (tid < NTOK) ? __expf(d - M) : 0.f;
  float ssum = e;
  #pragma unroll
  for (int off = 32; off; off >>= 1) ssum += __shfl_xor(ssum, off, 64);
  if (l == 0) red[4 + w] = ssum;
  __syncthreads();
  const float S = red[4] + red[5] + red[6] + red[7];
  attn[tid] = e / S;
  __syncthreads();
  float o = 0.f;
  if (tid < 64) {
    for (int j = 0; j < NTOK; ++j)
      o += attn[j] * V[rowbase + (size_t)j * 768 + tid];
  }
  return o;
}

__global__ void cls_attn(const float* __restrict__ Q, const float* __restrict__ K,
                         const float* __restrict__ V, float* __restrict__ ATT) {
  __shared__ float q[64];
  __shared__ float attn[256];
  __shared__ float red[8];
  const int b = blockIdx.x / 12, h = blockIdx.x % 12;
  const size_t rowbase = ((size_t)b * NTOK) * 768 + h * 64;
  float o = cls_attn_body(Q, K, V, rowbase, q, attn, red);
  if (threadIdx.x < 64) ATT[rowbase + threadIdx.x] = o;
}

// -------- patch tokens, fast path: 1 wave = 4 patches, 16 lanes/patch ------
__global__ __launch_bounds__(256) void patch_attn4_b(
    const float* __restrict__ Q, const float* __restrict__ K,
    const float* __restrict__ V, unsigned short* __restrict__ ATT) {
  const int swb = xcd_swizzle(blockIdx.x, PATCH_NBLK);
  const int wu = swb * 4 + (threadIdx.x >> 6);   // (b, pq, h), h fastest
  const int l = threadIdx.x & 63;
  const int t16 = l & 15, pg = l >> 4;
  const int h = wu % 12;
  const int t2 = wu / 12;
  const int pq = t2 % 49;
  const int b = t2 / 49;
  const int p = pq * 4 + pg;                     // 0..195
  const int r = p / 14, c = p % 14;
  const size_t ib = ((size_t)b * NTOK) * 768 + h * 64 + t16 * 4;

  const float4 q = *(const float4*)(Q + ib + (size_t)(p + 1) * 768);

  float s[9];
  int tok[9];
  #pragma unroll
  for (int jj = 0; jj < 9; ++jj) {
    const int nr = r + jj / 3 - 1, nc = c + jj % 3 - 1;
    const bool ok = ((unsigned)nr < 14u) && ((unsigned)nc < 14u);
    tok[jj] = ok ? (1 + nr * 14 + nc) : (p + 1);
    const float4 kk = *(const float4*)(K + ib + (size_t)tok[jj] * 768);
    float d = q.x * kk.x + q.y * kk.y + q.z * kk.z + q.w * kk.w;
    d += __shfl_xor(d, 1);
    d += __shfl_xor(d, 2);
    d += __shfl_xor(d, 4);
    d += __shfl_xor(d, 8);                       // 16-lane group sum
    s[jj] = ok ? d * 0.125f : -3e38f;
  }
  float m = s[0];
  #pragma unroll
  for (int jj = 1; jj < 9; ++jj) m = fmaxf(m, s[jj]);
  float sum = 0.f;
  #pragma unroll
  for (int jj = 0; jj < 9; ++jj) { s[jj] = __expf(s[jj] - m); sum += s[jj]; }
  const float inv = 1.f / sum;

  float4 o = {0.f, 0.f, 0.f, 0.f};
  #pragma unroll
  for (int jj = 0; jj < 9; ++jj) {
    const float4 vv = *(const float4*)(V + ib + (size_t)tok[jj] * 768);
    o.x += s[jj] * vv.x; o.y += s[jj] * vv.y;
    o.z += s[jj] * vv.z; o.w += s[jj] * vv.w;
  }
  o.x *= inv; o.y *= inv; o.z *= inv; o.w *= inv;
  unsigned short t4[4] = { f2b(o.x), f2b(o.y), f2b(o.z), f2b(o.w) };
  *(ushort2*)&ATT[ib + (size_t)(p + 1) * 768] = *(const ushort2*)&t4[0];
  *(ushort2*)&ATT[ib + (size_t)(p + 1) * 768 + 2] = *(const ushort2*)&t4[2];
}

// fallback scalar patch kernel (fp32 out)
__device__ __forceinline__ float patch_attn_body(const float* __restrict__ Q,
                                                 const float* __restrict__ K,
                                                 const float* __restrict__ V,
                                                 const size_t base, const int p,
                                                 const int r, const int c) {
  const float qd = Q[base + (size_t)(p + 1) * 768];

  float s[9];
  int tok[9];
  #pragma unroll
  for (int jj = 0; jj < 9; ++jj) {
    const int nr = r + jj / 3 - 1, nc = c + jj % 3 - 1;
    const bool ok = ((unsigned)nr < 14u) && ((unsigned)nc < 14u);
    tok[jj] = ok ? (1 + nr * 14 + nc) : (p + 1);
    float d = qd * K[base + (size_t)tok[jj] * 768];
    #pragma unroll
    for (int off = 32; off; off >>= 1) d += __shfl_xor(d, off, 64);
    s[jj] = ok ? d * 0.125f : -3e38f;
  }
  float m = s[0];
  #pragma unroll
  for (int jj = 1; jj < 9; ++jj) m = fmaxf(m, s[jj]);
  float sum = 0.f;
  #pragma unroll
  for (int jj = 0; jj < 9; ++jj) { s[jj] = __expf(s[jj] - m); sum += s[jj]; }
  const float inv = 1.f / sum;
  float o = 0.f;
  #pragma unroll
  for (int jj = 0; jj < 9; ++jj) o += s[jj] * V[base + (size_t)tok[jj] * 768];
  return o * inv;
}

__global__ void patch_attn(const float* __restrict__ Q, const float* __restrict__ K,
                           const float* __restrict__ V, float* __restrict__ ATT) {
  const int wgid = blockIdx.x * 4 + (threadIdx.x >> 6);
  const int l = threadIdx.x & 63;
  const int h = wgid % 12;
  const int t2 = wgid / 12;
  const int p = t2 % 196;
  const int b = t2 / 196;
  const int r = p / 14, c = p % 14;
  const size_t base = ((size_t)b * NTOK) * 768 + h * 64 + l;
  float o = patch_attn_body(Q, K, V, base, p, r, c);
  ATT[base + (size_t)(p + 1) * 768] = o;
}

extern "C" void kernel_launch(void* const* d_in, const int* in_sizes, int n_in,
                              void* d_out, int out_size, void* d_ws, size_t ws_size,
                              hipStream_t stream) {
  const float* x  = (const float*)d_in[0];
  const float* y  = (const float*)d_in[1];
  const float* Wq = (const float*)d_in[2];
  const float* bq = (const float*)d_in[3];
  const float* Wk = (const float*)d_in[4];
  const float* bk = (const float*)d_in[5];
  const float* Wv = (const float*)d_in[6];
  const float* bv = (const float*)d_in[7];
  const float* Wo = (const float*)d_in[8];
  const float* bo = (const float*)d_in[9];
  float* out = (float*)d_out;

  unsigned short* WqT = (unsigned short*)d_ws;
  unsigned short* WkT = WqT + W_ELEMS;
  unsigned short* WvT = WkT + W_ELEMS;
  unsigned short* WoT = WvT + W_ELEMS;

  transpose768x4<<<dim3(2304, 4), 256, 0, stream>>>(Wq, Wk, Wv, Wo, WqT, WkT, WvT, WoT);

  const size_t need_full = 4 * W_ELEMS * sizeof(unsigned short)
                         + BUF_ELEMS_FULL * sizeof(unsigned short)   // Xb/Yb/ATTb
                         + 3 * BUF_ELEMS_FULL * sizeof(float);       // K,V,Q
  if (ws_size >= need_full) {
    // ---- full-batch path ----
    // R1 (38.7 MB) hosts, strictly sequentially: Xb -> Yb -> ATTb.
    unsigned short* R1 = WoT + W_ELEMS;
    float* Kc = (float*)(R1 + BUF_ELEMS_FULL);
    float* Vc = Kc + BUF_ELEMS_FULL;
    float* Qc = Vc + BUF_ELEMS_FULL;

    const int n8 = (int)(BUF_ELEMS_FULL / 8);
    cvt8<<<n8 / 256, 256, 0, stream>>>(x, R1, n8);                 // Xb
    gemm_bf16<<<NB_FULL, 256, 0, stream>>>(R1, WkT, bk, Kc);
    gemm_bf16<<<NB_FULL, 256, 0, stream>>>(R1, WvT, bv, Vc);
    cvt8<<<n8 / 256, 256, 0, stream>>>(y, R1, n8);                 // Yb (Xb dead)
    gemm_bf16<<<NB_FULL, 256, 0, stream>>>(R1, WqT, bq, Qc);
    cls_attn_b<<<BATCH * 12, 256, 0, stream>>>(Qc, Kc, Vc, R1);    // ATTb (Yb dead)
    patch_attn4_b<<<PATCH_NBLK, 256, 0, stream>>>(Qc, Kc, Vc, R1);
    gemm_bf16<<<NB_FULL, 256, 0, stream>>>(R1, WoT, bo, out);
  } else {
    // ---- fallback: old 16-chunk flow (ws ~19 MB) ----
    float* Kc = (float*)(WoT + W_ELEMS);
    float* Vc = Kc + BUF_ELEMS_CHUNK;
    float* Qc = Vc + BUF_ELEMS_CHUNK;

    for (int c = 0; c < NCHUNK; ++c) {
      const float* xc = x + (size_t)c * BUF_ELEMS_CHUNK;
      const float* yc = y + (size_t)c * BUF_ELEMS_CHUNK;
      qkv_gemm<<<dim3(18, MTILES_CHUNK), 256, 0, stream>>>(
          xc, yc, WkT, WvT, WqT, bk, bv, bq, Kc, Vc, Qc, MC_CHUNK);
      cls_attn<<<CHUNK_B * 12, 256, 0, stream>>>(Qc, Kc, Vc, Qc);
      patch_attn<<<(CHUNK_B * 196 * 12) / 4, 256, 0, stream>>>(Qc, Kc, Vc, Qc);
      gemm_bt<<<dim3(6, MTILES_CHUNK), 256, 0, stream>>>(Qc, WoT, bo,
                                                         out + (size_t)c * BUF_ELEMS_CHUNK, MC_CHUNK);
    }
  }
}

// Round 6
// 496.537 us; speedup vs baseline: 5.5880x; 1.0309x over previous
//
#include <hip/hip_runtime.h>

// CrossAttention: x_qkv->K,V ; y_q->Q ; CLS full attn + patch 3x3 local attn ; @Wo+bo
// I/O fp32. Internals: bf16 MFMA GEMMs.
//
// THIS VERSION (vs round-5):
//  - gemm core: 3-stage LDS pipeline (3 bufs, 48KB, 3 blocks/CU) with counted
//    vmcnt(8) -> prefetch distance 2 K-steps (~600+cyc), covers L3 latency.
//  - K+V GEMMs merged into ONE 2364-block launch (by-major, mat inner):
//    amortizes the grid tail, K/V blocks share A-panels in L2.
//  - patch_attn: LDS-staged. Block = (image, head, 2 patch-rows): stages the
//    4 needed K/V token-rows (28.7KB) once, dot/PV read ds_read_b128
//    (bank-conflict-free). Kills the 9x K/V re-read that streamed 1.4GB
//    from L3. Math order identical to round-5 -> bit-identical output.
// cvt8 / cls_attn_b / transpose unchanged.

typedef __bf16 bf16x8 __attribute__((ext_vector_type(8)));
typedef float f32x4 __attribute__((ext_vector_type(4)));

#define NTOK 197
#define BATCH 128
#define MROWS (BATCH * NTOK)            // 25216, divisible by 128
#define MTILES_FULL (MROWS / 128)       // 197
#define NB_FULL (6 * MTILES_FULL)       // 1182 blocks per GEMM
#define NB_KV (2 * NB_FULL)             // 2364 merged K+V
#define W_ELEMS ((size_t)768 * 768)
#define BUF_ELEMS_FULL ((size_t)MROWS * 768)
#define PSTRIPS 7
#define PATCH2_NBLK (BATCH * PSTRIPS * 12)  // 10752 (%8==0)

// fallback chunked config (small-ws safety net)
#define CHUNK_B 8
#define NCHUNK 16
#define MC_CHUNK (CHUNK_B * NTOK)       // 1576
#define MTILES_CHUNK 13
#define BUF_ELEMS_CHUNK ((size_t)MC_CHUNK * 768)

__device__ __forceinline__ unsigned short f2b(float f) {
  unsigned int x = __float_as_uint(f);
  x += 0x7fff + ((x >> 16) & 1);          // RNE
  return (unsigned short)(x >> 16);
}

__device__ __forceinline__ uint4 cvt8pack(float4 f0, float4 f1) {
  unsigned short t8[8] = { f2b(f0.x), f2b(f0.y), f2b(f0.z), f2b(f0.w),
                           f2b(f1.x), f2b(f1.y), f2b(f1.z), f2b(f1.w) };
  return *(const uint4*)t8;
}

#define GLOAD_LDS16(gp, lp)                                                   \
  __builtin_amdgcn_global_load_lds(                                           \
      (const __attribute__((address_space(1))) void*)(gp),                    \
      (__attribute__((address_space(3))) void*)(lp), 16, 0, 0)

// bijective XCD-chunk swizzle (m204)
__device__ __forceinline__ int xcd_swizzle(int bid, int nb) {
  const int q = nb >> 3, r = nb & 7;
  const int xcd = bid & 7, i = bid >> 3;
  return (xcd < r ? xcd * (q + 1) : r * (q + 1) + (xcd - r) * q) + i;
}

// -------- weight transpose+convert: Wt[n*768+k] = bf16(W[k*768+n]) --------
__global__ void transpose768x4(const float* __restrict__ s0, const float* __restrict__ s1,
                               const float* __restrict__ s2, const float* __restrict__ s3,
                               unsigned short* __restrict__ d0, unsigned short* __restrict__ d1,
                               unsigned short* __restrict__ d2, unsigned short* __restrict__ d3) {
  const float* src;
  unsigned short* dst;
  switch (blockIdx.y) {
    case 0: src = s0; dst = d0; break;
    case 1: src = s1; dst = d1; break;
    case 2: src = s2; dst = d2; break;
    default: src = s3; dst = d3; break;
  }
  int idx = blockIdx.x * 256 + threadIdx.x;   // 589824 total
  int n = idx / 768, k = idx % 768;
  dst[idx] = f2b(src[k * 768 + n]);
}

// -------- fp32 -> bf16 bulk convert, 8 elems/thread --------
__global__ void cvt8(const float* __restrict__ src, unsigned short* __restrict__ dst,
                     const int n8) {
  int i = blockIdx.x * 256 + threadIdx.x;
  if (i >= n8) return;
  const float4* p = (const float4*)(src + (size_t)i * 8);
  *(uint4*)(dst + (size_t)i * 8) = cvt8pack(p[0], p[1]);
}

// -------- MFMA tile helpers (128x128 tile, 4 waves 2x2, 4x4 frags) --------
__device__ __forceinline__ void mfma_tile(const unsigned short* sA, const unsigned short* sB,
                                          f32x4 (&acc)[4][4],
                                          const int wr, const int wc,
                                          const int lane16, const int quad) {
  bf16x8 af[4], bf_[4];
  #pragma unroll
  for (int i = 0; i < 4; ++i)
    af[i] = *(const bf16x8*)&sA[(wr * 64 + i * 16 + lane16) * 32 + quad * 8];
  #pragma unroll
  for (int j = 0; j < 4; ++j)
    bf_[j] = *(const bf16x8*)&sB[(wc * 64 + j * 16 + lane16) * 32 + quad * 8];
  #pragma unroll
  for (int i = 0; i < 4; ++i)
    #pragma unroll
    for (int j = 0; j < 4; ++j)
      acc[i][j] = __builtin_amdgcn_mfma_f32_16x16x32_bf16(af[i], bf_[j], acc[i][j], 0, 0, 0);
}

__device__ __forceinline__ void epilogue128(f32x4 (&acc)[4][4], const float* __restrict__ bias,
                                            float* __restrict__ C, const int row0, const int n0,
                                            const int wr, const int wc,
                                            const int lane16, const int quad) {
  #pragma unroll
  for (int j = 0; j < 4; ++j) {
    const int col = n0 + wc * 64 + j * 16 + lane16;
    const float bv = bias[col];
    #pragma unroll
    for (int i = 0; i < 4; ++i) {
      const int r0 = row0 + wr * 64 + i * 16 + quad * 4;
      #pragma unroll
      for (int r = 0; r < 4; ++r)
        C[(size_t)(r0 + r) * 768 + col] = acc[i][j][r] + bv;
    }
  }
}

// -------- GEMM core: 3-stage pipeline, counted vmcnt. lds = 3 x 8192 ushort.
__device__ __forceinline__ void gemm_core3(
    const unsigned short* __restrict__ A, const unsigned short* __restrict__ Bt,
    const float* __restrict__ bias, float* __restrict__ C,
    const int row0, const int n0, unsigned short* lds) {
  const int tid = threadIdx.x;
  const int l = tid & 63, w = tid >> 6;
  const int wr = w >> 1, wc = w & 1;
  const int lane16 = l & 15, quad = l >> 4;
  const int rr = tid >> 2, c8 = (tid & 3) * 8;
  const int wbase = (tid & 192) * 8;           // wave-uniform LDS chunk base

  const unsigned short* a0 = A + (size_t)(row0 + rr) * 768 + c8;
  const unsigned short* a1 = a0 + (size_t)64 * 768;
  const unsigned short* b0 = Bt + (size_t)(n0 + rr) * 768 + c8;
  const unsigned short* b1 = b0 + (size_t)64 * 768;

  f32x4 acc[4][4] = {};

#define STAGE3(B, kt) do { const int ko = (kt) * 32;                  \
    unsigned short* lb = lds + (B) * 8192;                            \
    GLOAD_LDS16(a0 + ko, lb + wbase);                                 \
    GLOAD_LDS16(a1 + ko, lb + wbase + 2048);                          \
    GLOAD_LDS16(b0 + ko, lb + 4096 + wbase);                          \
    GLOAD_LDS16(b1 + ko, lb + 4096 + wbase + 2048); } while (0)

  STAGE3(0, 0);
  STAGE3(1, 1);
  int cur = 0, stg = 2;
  for (int kt = 0; kt < 22; ++kt) {
    STAGE3(stg, kt + 2);                               // 12 loads in flight
    asm volatile("s_waitcnt vmcnt(8)" ::: "memory");   // tile kt landed
    __builtin_amdgcn_s_barrier();
    __builtin_amdgcn_sched_barrier(0);
    mfma_tile(lds + cur * 8192, lds + cur * 8192 + 4096, acc, wr, wc, lane16, quad);
    __builtin_amdgcn_s_barrier();                      // reads done before overwrite
    cur = (cur == 2) ? 0 : cur + 1;
    stg = (stg == 2) ? 0 : stg + 1;
  }
  // kt = 22
  asm volatile("s_waitcnt vmcnt(4)" ::: "memory");
  __builtin_amdgcn_s_barrier();
  __builtin_amdgcn_sched_barrier(0);
  mfma_tile(lds + cur * 8192, lds + cur * 8192 + 4096, acc, wr, wc, lane16, quad);
  cur = (cur == 2) ? 0 : cur + 1;
  // kt = 23
  asm volatile("s_waitcnt vmcnt(0)" ::: "memory");
  __builtin_amdgcn_s_barrier();
  __builtin_amdgcn_sched_barrier(0);
  mfma_tile(lds + cur * 8192, lds + cur * 8192 + 4096, acc, wr, wc, lane16, quad);
#undef STAGE3

  epilogue128(acc, bias, C, row0, n0, wr, wc, lane16, quad);
}

// single-output GEMM (Q, O projections)
__global__ __launch_bounds__(256, 3) void gemm_bf16(
    const unsigned short* __restrict__ A, const unsigned short* __restrict__ Bt,
    const float* __restrict__ bias, float* __restrict__ C) {
  __shared__ unsigned short lds[3 * 8192];
  const int swz = xcd_swizzle(blockIdx.x, NB_FULL);
  const int by = swz / 6, bx = swz % 6;
  gemm_core3(A, Bt, bias, C, by * 128, bx * 128, lds);
}

// merged K+V GEMM: 2364 blocks, by-major so K/V blocks of one row-panel
// are adjacent (A-panel shared in L2).
__global__ __launch_bounds__(256, 3) void gemm_bf16_kv(
    const unsigned short* __restrict__ Xb,
    const unsigned short* __restrict__ WkT, const unsigned short* __restrict__ WvT,
    const float* __restrict__ bk, const float* __restrict__ bv,
    float* __restrict__ K, float* __restrict__ V) {
  __shared__ unsigned short lds[3 * 8192];
  const int swz = xcd_swizzle(blockIdx.x, NB_KV);
  const int by = swz / 12;
  const int rem = swz % 12;
  const int mat = rem / 6, bx = rem % 6;
  const unsigned short* Bt = mat ? WvT : WkT;
  const float* bias = mat ? bv : bk;
  float* C = mat ? V : K;
  gemm_core3(Xb, Bt, bias, C, by * 128, bx * 128, lds);
}

// ==================== fallback (chunked) GEMM bodies ====================
__device__ __forceinline__ void gemm_body_f32A(
    const float* __restrict__ A, const unsigned short* __restrict__ Wt,
    const float* __restrict__ bias, float* __restrict__ C,
    const int row0, const int n0, const int Mrows, unsigned short* sAB) {
  const int tid = threadIdx.x;
  const int l = tid & 63, w = tid >> 6;
  const int wr = w >> 1, wc = w & 1;
  const int lane16 = l & 15, quad = l >> 4;

  f32x4 acc[4][4] = {};

  for (int kt = 0; kt < 24; ++kt) {
    const int k0 = kt * 32;
    #pragma unroll
    for (int i = 0; i < 2; ++i) {
      const int ch = i * 256 + tid;
      const int rr2 = ch >> 2;
      const int c82 = (ch & 3) * 8;
      int ra = row0 + rr2; if (ra > Mrows - 1) ra = Mrows - 1;
      const float* ap = A + (size_t)ra * 768 + k0 + c82;
      float4 q0 = *(const float4*)ap;
      float4 q1 = *(const float4*)(ap + 4);
      *(uint4*)&sAB[rr2 * 32 + c82] = cvt8pack(q0, q1);
      uint4 vb = *(const uint4*)(Wt + (size_t)(n0 + rr2) * 768 + k0 + c82);
      *(uint4*)&sAB[4096 + rr2 * 32 + c82] = vb;
    }
    __syncthreads();
    mfma_tile(sAB, sAB + 4096, acc, wr, wc, lane16, quad);
    __syncthreads();
  }
  #pragma unroll
  for (int j = 0; j < 4; ++j) {
    const int col = n0 + wc * 64 + j * 16 + lane16;
    const float bv = bias[col];
    #pragma unroll
    for (int i = 0; i < 4; ++i) {
      const int r0 = row0 + wr * 64 + i * 16 + quad * 4;
      #pragma unroll
      for (int r = 0; r < 4; ++r)
        if (r0 + r < Mrows)
          C[(size_t)(r0 + r) * 768 + col] = acc[i][j][r] + bv;
    }
  }
}

__global__ __launch_bounds__(256, 2) void qkv_gemm(
    const float* __restrict__ X, const float* __restrict__ Y,
    const unsigned short* __restrict__ WkT, const unsigned short* __restrict__ WvT,
    const unsigned short* __restrict__ WqT,
    const float* __restrict__ bk, const float* __restrict__ bv, const float* __restrict__ bq,
    float* __restrict__ K, float* __restrict__ V, float* __restrict__ Q,
    const int Mrows) {
  __shared__ unsigned short sAB[8192];
  const int mat = blockIdx.x / 6;
  const int n0 = (blockIdx.x % 6) * 128;
  const float* A = (mat == 2) ? Y : X;
  const unsigned short* Wt = (mat == 0) ? WkT : (mat == 1) ? WvT : WqT;
  const float* bias = (mat == 0) ? bk : (mat == 1) ? bv : bq;
  float* C = (mat == 0) ? K : (mat == 1) ? V : Q;
  gemm_body_f32A(A, Wt, bias, C, blockIdx.y * 128, n0, Mrows, sAB);
}

__global__ __launch_bounds__(256, 2) void gemm_bt(
    const float* __restrict__ A, const unsigned short* __restrict__ Wt,
    const float* __restrict__ bias, float* __restrict__ C, const int Mrows) {
  __shared__ unsigned short sAB[8192];
  gemm_body_f32A(A, Wt, bias, C, blockIdx.y * 128, blockIdx.x * 128, Mrows, sAB);
}

// ==================== attention ====================
// CLS full attention: dots wave-parallel, V-accum uses ALL 256 threads.
__global__ void cls_attn_b(const float* __restrict__ Q, const float* __restrict__ K,
                           const float* __restrict__ V, unsigned short* __restrict__ ATT) {
  __shared__ float q[64];
  __shared__ float attn[256];
  __shared__ float red[8];
  __shared__ float part[4][64];
  const int tid = threadIdx.x, l = tid & 63, w = tid >> 6;
  const int b = blockIdx.x / 12, h = blockIdx.x % 12;
  const size_t rowbase = ((size_t)b * NTOK) * 768 + h * 64;

  if (tid < 64) q[tid] = Q[rowbase + tid];
  __syncthreads();

  float d = -3e38f;
  if (tid < NTOK) {
    const float4* Kp = (const float4*)(K + rowbase + (size_t)tid * 768);
    float s = 0.f;
    #pragma unroll
    for (int u = 0; u < 16; ++u) {
      float4 kk = Kp[u];
      s += q[u * 4 + 0] * kk.x + q[u * 4 + 1] * kk.y
         + q[u * 4 + 2] * kk.z + q[u * 4 + 3] * kk.w;
    }
    d = s * 0.125f;
  }
  float m = d;
  #pragma unroll
  for (int off = 32; off; off >>= 1) m = fmaxf(m, __shfl_xor(m, off, 64));
  if (l == 0) red[w] = m;
  __syncthreads();
  const float M = fmaxf(fmaxf(red[0], red[1]), fmaxf(red[2], red[3]));
  float e = (tid < NTOK) ? __expf(d - M) : 0.f;
  float ssum = e;
  #pragma unroll
  for (int off = 32; off; off >>= 1) ssum += __shfl_xor(ssum, off, 64);
  if (l == 0) red[4 + w] = ssum;
  __syncthreads();
  const float S = red[4] + red[5] + red[6] + red[7];
  attn[tid] = e / S;
  __syncthreads();

  const int dd = tid & 63, jg = tid >> 6;
  float o = 0.f;
  for (int j = jg; j < NTOK; j += 4)
    o += attn[j] * V[rowbase + (size_t)j * 768 + dd];
  part[jg][dd] = o;
  __syncthreads();
  if (tid < 64) {
    const float r = part[0][tid] + part[1][tid] + part[2][tid] + part[3][tid];
    ATT[rowbase + tid] = f2b(r);
  }
}

// fallback fp32-out CLS (old structure)
__device__ __forceinline__ float cls_attn_body(const float* __restrict__ Q,
                                               const float* __restrict__ K,
                                               const float* __restrict__ V,
                                               const size_t rowbase,
                                               float* q, float* attn, float* red) {
  const int tid = threadIdx.x, l = tid & 63, w = tid >> 6;
  if (tid < 64) q[tid] = Q[rowbase + tid];
  __syncthreads();

  float d = -3e38f;
  if (tid < NTOK) {
    const float4* Kp = (const float4*)(K + rowbase + (size_t)tid * 768);
    float s = 0.f;
    #pragma unroll
    for (int u = 0; u < 16; ++u) {
      float4 kk = Kp[u];
      s += q[u * 4 + 0] * kk.x + q[u * 4 + 1] * kk.y
         + q[u * 4 + 2] * kk.z + q[u * 4 + 3] * kk.w;
    }
    d = s * 0.125f;
  }
  float m = d;
  #pragma unroll
  for (int off = 32; off; off >>= 1) m = fmaxf(m, __shfl_xor(m, off, 64));
  if (l == 0) red[w] = m;
  __syncthreads();
  const float M = fmaxf(fmaxf(red[0], red[1]), fmaxf(red[2], red[3]));
  float e = (tid < NTOK) ? __expf(d - M) : 0.f;
  float ssum = e;
  #pragma unroll
  for (int off = 32; off; off >>= 1) ssum += __shfl_xor(ssum, off, 64);
  if (l == 0) red[4 + w] = ssum;
  __syncthreads();
  const float S = red[4] + red[5] + red[6] + red[7];
  attn[tid] = e / S;
  __syncthreads();
  float o = 0.f;
  if (tid < 64) {
    for (int j = 0; j < NTOK; ++j)
      o += attn[j] * V[rowbase + (size_t)j * 768 + tid];
  }
  return o;
}

__global__ void cls_attn(const float* __restrict__ Q, const float* __restrict__ K,
                         const float* __restrict__ V, float* __restrict__ ATT) {
  __shared__ float q[64];
  __shared__ float attn[256];
  __shared__ float red[8];
  const int b = blockIdx.x / 12, h = blockIdx.x % 12;
  const size_t rowbase = ((size_t)b * NTOK) * 768 + h * 64;
  float o = cls_attn_body(Q, K, V, rowbase, q, attn, red);
  if (threadIdx.x < 64) ATT[rowbase + threadIdx.x] = o;
}

// -------- patch tokens, LDS-staged: block = (b, h, strip of 2 patch-rows) --
// Stages the 4 token-rows the strip touches (K,V fp32: 28.7KB) then 7 waves
// x 4 patches run the 16-lane/patch dot/softmax/PV from LDS.
__global__ __launch_bounds__(448, 7) void patch_attn_lds(
    const float* __restrict__ Q, const float* __restrict__ K,
    const float* __restrict__ V, unsigned short* __restrict__ ATT) {
  __shared__ float Kl[4 * 14 * 64];
  __shared__ float Vl[4 * 14 * 64];
  const int bid = xcd_swizzle(blockIdx.x, PATCH2_NBLK);
  const int h = bid % 12;
  const int t2 = bid / 12;
  const int s = t2 % PSTRIPS;          // strip: patch rows 2s, 2s+1
  const int b = t2 / PSTRIPS;
  const int tid = threadIdx.x;

  // ---- stage K/V token-rows tr = 2s-1 .. 2s+2 (lr=0..3) ----
  {
    const int fi = tid * 8;            // 0..3583 (448*8 = 3584 = 4*14*64)
    const int lr = fi / 896;           // 14*64
    const int rem = fi - lr * 896;     // nc*64 + d0
    const int tr = s * 2 - 1 + lr;
    if ((unsigned)tr < 14u) {
      const int tok = 1 + tr * 14 + (rem >> 6);
      const unsigned goff = (unsigned)((b * NTOK + tok) * 768 + h * 64 + (rem & 63));
      *(float4*)&Kl[fi]     = *(const float4*)(K + goff);
      *(float4*)&Kl[fi + 4] = *(const float4*)(K + goff + 4);
      *(float4*)&Vl[fi]     = *(const float4*)(V + goff);
      *(float4*)&Vl[fi + 4] = *(const float4*)(V + goff + 4);
    }
  }
  __syncthreads();

  const int l = tid & 63;
  const int t16 = l & 15, pg = l >> 4;
  const int lp = (tid >> 6) * 4 + pg;  // 0..27 local patch
  const int prl = lp / 14, pc = lp - prl * 14;
  const int r = s * 2 + prl, c = pc;
  const int p = r * 14 + c;
  const unsigned qoff = (unsigned)((b * NTOK + p + 1) * 768 + h * 64 + t16 * 4);

  const float4 q = *(const float4*)(Q + qoff);

  float s9[9];
  int loff[9];
  #pragma unroll
  for (int jj = 0; jj < 9; ++jj) {
    const int dj = jj / 3, dc = jj % 3 - 1;
    const int nr = r + dj - 1, nc = c + dc;
    const bool ok = ((unsigned)nr < 14u) && ((unsigned)nc < 14u);
    const int lr = ok ? (prl + dj) : (prl + 1);
    const int lc = ok ? nc : c;
    loff[jj] = (lr * 14 + lc) * 64 + t16 * 4;
    const float4 kk = *(const float4*)&Kl[loff[jj]];
    float d = q.x * kk.x + q.y * kk.y + q.z * kk.z + q.w * kk.w;
    d += __shfl_xor(d, 1);
    d += __shfl_xor(d, 2);
    d += __shfl_xor(d, 4);
    d += __shfl_xor(d, 8);
    s9[jj] = ok ? d * 0.125f : -3e38f;
  }
  float m = s9[0];
  #pragma unroll
  for (int jj = 1; jj < 9; ++jj) m = fmaxf(m, s9[jj]);
  float sum = 0.f;
  #pragma unroll
  for (int jj = 0; jj < 9; ++jj) { s9[jj] = __expf(s9[jj] - m); sum += s9[jj]; }
  const float inv = 1.f / sum;

  float4 o = {0.f, 0.f, 0.f, 0.f};
  #pragma unroll
  for (int jj = 0; jj < 9; ++jj) {
    const float4 vv = *(const float4*)&Vl[loff[jj]];
    o.x += s9[jj] * vv.x; o.y += s9[jj] * vv.y;
    o.z += s9[jj] * vv.z; o.w += s9[jj] * vv.w;
  }
  o.x *= inv; o.y *= inv; o.z *= inv; o.w *= inv;
  unsigned short t4[4] = { f2b(o.x), f2b(o.y), f2b(o.z), f2b(o.w) };
  *(ushort2*)&ATT[qoff] = *(const ushort2*)&t4[0];
  *(ushort2*)&ATT[qoff + 2] = *(const ushort2*)&t4[2];
}

// fallback scalar patch kernel (fp32 out)
__device__ __forceinline__ float patch_attn_body(const float* __restrict__ Q,
                                                 const float* __restrict__ K,
                                                 const float* __restrict__ V,
                                                 const size_t base, const int p,
                                                 const int r, const int c) {
  const float qd = Q[base + (size_t)(p + 1) * 768];

  float s[9];
  int tok[9];
  #pragma unroll
  for (int jj = 0; jj < 9; ++jj) {
    const int nr = r + jj / 3 - 1, nc = c + jj % 3 - 1;
    const bool ok = ((unsigned)nr < 14u) && ((unsigned)nc < 14u);
    tok[jj] = ok ? (1 + nr * 14 + nc) : (p + 1);
    float d = qd * K[base + (size_t)tok[jj] * 768];
    #pragma unroll
    for (int off = 32; off; off >>= 1) d += __shfl_xor(d, off, 64);
    s[jj] = ok ? d * 0.125f : -3e38f;
  }
  float m = s[0];
  #pragma unroll
  for (int jj = 1; jj < 9; ++jj) m = fmaxf(m, s[jj]);
  float sum = 0.f;
  #pragma unroll
  for (int jj = 0; jj < 9; ++jj) { s[jj] = __expf(s[jj] - m); sum += s[jj]; }
  const float inv = 1.f / sum;
  float o = 0.f;
  #pragma unroll
  for (int jj = 0; jj < 9; ++jj) o += s[jj] * V[base + (size_t)tok[jj] * 768];
  return o * inv;
}

__global__ void patch_attn(const float* __restrict__ Q, const float* __restrict__ K,
                           const float* __restrict__ V, float* __restrict__ ATT) {
  const int wgid = blockIdx.x * 4 + (threadIdx.x >> 6);
  const int l = threadIdx.x & 63;
  const int h = wgid % 12;
  const int t2 = wgid / 12;
  const int p = t2 % 196;
  const int b = t2 / 196;
  const int r = p / 14, c = p % 14;
  const size_t base = ((size_t)b * NTOK) * 768 + h * 64 + l;
  float o = patch_attn_body(Q, K, V, base, p, r, c);
  ATT[base + (size_t)(p + 1) * 768] = o;
}

extern "C" void kernel_launch(void* const* d_in, const int* in_sizes, int n_in,
                              void* d_out, int out_size, void* d_ws, size_t ws_size,
                              hipStream_t stream) {
  const float* x  = (const float*)d_in[0];
  const float* y  = (const float*)d_in[1];
  const float* Wq = (const float*)d_in[2];
  const float* bq = (const float*)d_in[3];
  const float* Wk = (const float*)d_in[4];
  const float* bk = (const float*)d_in[5];
  const float* Wv = (const float*)d_in[6];
  const float* bv = (const float*)d_in[7];
  const float* Wo = (const float*)d_in[8];
  const float* bo = (const float*)d_in[9];
  float* out = (float*)d_out;

  unsigned short* WqT = (unsigned short*)d_ws;
  unsigned short* WkT = WqT + W_ELEMS;
  unsigned short* WvT = WkT + W_ELEMS;
  unsigned short* WoT = WvT + W_ELEMS;

  transpose768x4<<<dim3(2304, 4), 256, 0, stream>>>(Wq, Wk, Wv, Wo, WqT, WkT, WvT, WoT);

  const size_t need_full = 4 * W_ELEMS * sizeof(unsigned short)
                         + BUF_ELEMS_FULL * sizeof(unsigned short)   // Xb/Yb/ATTb
                         + 3 * BUF_ELEMS_FULL * sizeof(float);       // K,V,Q
  if (ws_size >= need_full) {
    // ---- full-batch path ----
    // R1 (38.7 MB) hosts, strictly sequentially: Xb -> Yb -> ATTb.
    unsigned short* R1 = WoT + W_ELEMS;
    float* Kc = (float*)(R1 + BUF_ELEMS_FULL);
    float* Vc = Kc + BUF_ELEMS_FULL;
    float* Qc = Vc + BUF_ELEMS_FULL;

    const int n8 = (int)(BUF_ELEMS_FULL / 8);
    cvt8<<<n8 / 256, 256, 0, stream>>>(x, R1, n8);                        // Xb
    gemm_bf16_kv<<<NB_KV, 256, 0, stream>>>(R1, WkT, WvT, bk, bv, Kc, Vc);
    cvt8<<<n8 / 256, 256, 0, stream>>>(y, R1, n8);                        // Yb
    gemm_bf16<<<NB_FULL, 256, 0, stream>>>(R1, WqT, bq, Qc);
    cls_attn_b<<<BATCH * 12, 256, 0, stream>>>(Qc, Kc, Vc, R1);           // ATTb
    patch_attn_lds<<<PATCH2_NBLK, 448, 0, stream>>>(Qc, Kc, Vc, R1);
    gemm_bf16<<<NB_FULL, 256, 0, stream>>>(R1, WoT, bo, out);
  } else {
    // ---- fallback: old 16-chunk flow (ws ~19 MB) ----
    float* Kc = (float*)(WoT + W_ELEMS);
    float* Vc = Kc + BUF_ELEMS_CHUNK;
    float* Qc = Vc + BUF_ELEMS_CHUNK;

    for (int c = 0; c < NCHUNK; ++c) {
      const float* xc = x + (size_t)c * BUF_ELEMS_CHUNK;
      const float* yc = y + (size_t)c * BUF_ELEMS_CHUNK;
      qkv_gemm<<<dim3(18, MTILES_CHUNK), 256, 0, stream>>>(
          xc, yc, WkT, WvT, WqT, bk, bv, bq, Kc, Vc, Qc, MC_CHUNK);
      cls_attn<<<CHUNK_B * 12, 256, 0, stream>>>(Qc, Kc, Vc, Qc);
      patch_attn<<<(CHUNK_B * 196 * 12) / 4, 256, 0, stream>>>(Qc, Kc, Vc, Qc);
      gemm_bt<<<dim3(6, MTILES_CHUNK), 256, 0, stream>>>(Qc, WoT, bo,
                                                         out + (size_t)c * BUF_ELEMS_CHUNK, MC_CHUNK);
    }
  }
}